// Round 3
// baseline (227.796 us; speedup 1.0000x reference)
//
#include <hip/hip_runtime.h>
#include <math.h>

#define LSEQ 4096   // D*H*W = 16*16*16
#define CIN  128
#define DI   64     // d_inner
#define NS   16     // d_state
#define NP   4      // parts
#define NJ   4      // jobs = (b, mixer) pairs
#define NSEQ 16     // NJ * NP independent mamba sequences
#define NC   128    // scan chunks
#define LC   32     // chunk length (NC*LC = LSEQ)
#define CPB  4      // chunks (waves) per block in scan kernels

__device__ __forceinline__ int mixer_of(const int* did, int j){
  if((j&1)==0) return 0;
  int d = did[j>>1];
  return 1 + (d < 1 ? d : 1);
}
__device__ __forceinline__ float silu_f(float x){ return x/(1.f+expf(-x)); }

// ---------------- K1: LN1 + in_proj. 32 l per block, w rows in registers ----------------
__global__ __launch_bounds__(256) void k1_ln_inproj(
  const float* __restrict__ x, const int* __restrict__ did,
  const float* __restrict__ ln_g, const float* __restrict__ ln_b,
  const float* __restrict__ in_w,
  float* __restrict__ xnb, float* __restrict__ xzr, float* __restrict__ zb)
{
  const int j = blockIdx.y, b = j>>1, t = threadIdx.x;
  const int l0 = blockIdx.x*32;
  const int m = mixer_of(did, j);
  __shared__ float s_x[128][33];    // [c][ll]
  __shared__ float s_xn[32][132];   // [ll][c]
  __shared__ float s_mu[32], s_rs[32];

  for(int idx=t; idx<4096; idx+=256){
    int c = idx>>5, ll = idx&31;
    s_x[c][ll] = x[((size_t)b*CIN+c)*LSEQ + l0+ll];
  }
  float wreg[32];
  {
    const float4* wp = (const float4*)(in_w + (size_t)m*4096 + (size_t)(t&127)*32);
    #pragma unroll
    for(int i=0;i<8;i++){
      float4 v = wp[i];
      wreg[i*4+0]=v.x; wreg[i*4+1]=v.y; wreg[i*4+2]=v.z; wreg[i*4+3]=v.w;
    }
  }
  __syncthreads();

  {
    const int wv = t>>6, lane = t&63;
    const int g = lane&7, lw = lane>>3;
    const int ll = wv*8+lw;
    float sum=0.f;
    #pragma unroll
    for(int k=0;k<16;k++) sum += s_x[g*16+k][ll];
    sum += __shfl_xor(sum,1); sum += __shfl_xor(sum,2); sum += __shfl_xor(sum,4);
    float mu = sum*(1.f/128.f);
    float vs=0.f;
    #pragma unroll
    for(int k=0;k<16;k++){ float dv = s_x[g*16+k][ll]-mu; vs += dv*dv; }
    vs += __shfl_xor(vs,1); vs += __shfl_xor(vs,2); vs += __shfl_xor(vs,4);
    if(g==0){ s_mu[ll]=mu; s_rs[ll]=rsqrtf(vs*(1.f/128.f)+1e-5f); }
  }
  __syncthreads();

  for(int idx=t; idx<4096; idx+=256){
    int ll = idx>>7, c = idx&127;
    float xn = (s_x[c][ll]-s_mu[ll])*s_rs[ll]*ln_g[m*128+c] + ln_b[m*128+c];
    s_xn[ll][c] = xn;
    xnb[((size_t)j*LSEQ + l0+ll)*128 + c] = xn;
  }
  __syncthreads();

  const int e = t&127, hh = t>>7;
  for(int ll=hh*16; ll<hh*16+16; ++ll){
    const float* xr = &s_xn[ll][0];
    #pragma unroll
    for(int q=0;q<4;q++){
      float acc=0.f;
      #pragma unroll
      for(int d=0;d<32;d++) acc += xr[q*32+d]*wreg[d];
      size_t base = ((size_t)(j*NP+q)*LSEQ + l0+ll)*64;
      if(e<64) xzr[base+e]=acc; else zb[base+e-64]=acc;
    }
  }
}

// ---------- K2: conv + SiLU + x_proj + dt/softplus. 64 l per block ----------
__global__ __launch_bounds__(256) void k2_conv_xproj(
  const int* __restrict__ did,
  const float* __restrict__ conv_w, const float* __restrict__ conv_b,
  const float* __restrict__ xp_w, const float* __restrict__ dt_w, const float* __restrict__ dt_b,
  const float* __restrict__ xzr, float* __restrict__ xib, float* __restrict__ dlb,
  float* __restrict__ bmb, float* __restrict__ cmb)
{
  const int seq = blockIdx.y, j = seq>>2, t = threadIdx.x;
  const int l0 = blockIdx.x*64;
  const int m = mixer_of(did, j);
  __shared__ float s_xz[67][64];
  __shared__ float s_xi[64][64];
  __shared__ float s_xpw[34][65];
  __shared__ float s_cwT[4][64];
  __shared__ float s_cb[64], s_dtw[128], s_dtb[64];
  __shared__ float s_dbc[64][2];

  for(int idx=t; idx<67*64; idx+=256){
    int row = idx>>6, d = idx&63, l = l0-3+row;
    s_xz[row][d] = (l>=0) ? xzr[((size_t)seq*LSEQ + l)*64 + d] : 0.f;
  }
  for(int idx=t; idx<34*64; idx+=256){
    int o = idx>>6, d = idx&63;
    s_xpw[o][d] = xp_w[m*2176 + idx];
  }
  { int k = t>>6, d = t&63; s_cwT[k][d] = conv_w[m*256 + d*4 + k]; }
  if(t<64){ s_cb[t]=conv_b[m*64+t]; s_dtb[t]=dt_b[m*64+t]; }
  if(t<128) s_dtw[t]=dt_w[m*128+t];
  __syncthreads();

  for(int it=0; it<16; ++it){
    int idx = t + it*256;
    int ll = idx>>6, d = idx&63;
    float xc = s_cb[d];
    #pragma unroll
    for(int k=0;k<4;k++) xc += s_xz[ll+k][d]*s_cwT[k][d];
    float xiv = silu_f(xc);
    s_xi[ll][d]=xiv;
    xib[(size_t)seq*LSEQ*64 + (size_t)(l0+ll)*64 + d] = xiv;
  }
  __syncthreads();

  {
    const int o = t&63, lg = t>>6;
    for(int ll=lg; ll<64; ll+=4){
      if(o<34){
        float acc=0.f;
        #pragma unroll
        for(int dd=0;dd<64;dd++) acc += s_xi[ll][dd]*s_xpw[o][dd];
        if(o<2) s_dbc[ll][o]=acc;
        else if(o<18) bmb[((size_t)seq*LSEQ + l0+ll)*16 + o-2]=acc;
        else          cmb[((size_t)seq*LSEQ + l0+ll)*16 + o-18]=acc;
      }
    }
  }
  __syncthreads();

  for(int it=0; it<16; ++it){
    int idx = t + it*256;
    int ll = idx>>6, d = idx&63;
    float dtv = s_dbc[ll][0]*s_dtw[d*2] + s_dbc[ll][1]*s_dtw[d*2+1] + s_dtb[d];
    float dlv = dtv>20.f ? dtv : log1pf(expf(dtv));
    dlb[(size_t)seq*LSEQ*64 + (size_t)(l0+ll)*64 + d] = dlv;
  }
}

// ---------------- K3a: per-chunk summaries. lane=d, s in registers ----------------
__global__ __launch_bounds__(256) void k3a_scan_pe(
  const int* __restrict__ did, const float* __restrict__ A_log,
  const float* __restrict__ xib, const float* __restrict__ dlb, const float* __restrict__ bmb,
  float* __restrict__ pb, float* __restrict__ eb)
{
  const int seq=blockIdx.y, j=seq>>2;
  const int wave=threadIdx.x>>6, d=threadIdx.x&63;
  const int chunk=blockIdx.x*CPB+wave;
  const int m=mixer_of(did,j);
  const float LOG2E=1.44269504f;
  float as[16];
  {
    const float4* ap=(const float4*)(A_log + (size_t)m*1024 + d*16);
    #pragma unroll
    for(int q=0;q<4;q++){ float4 v=ap[q];
      as[q*4+0]=-expf(v.x)*LOG2E; as[q*4+1]=-expf(v.y)*LOG2E;
      as[q*4+2]=-expf(v.z)*LOG2E; as[q*4+3]=-expf(v.w)*LOG2E; }
  }
  const float*  dp=dlb+(size_t)seq*LSEQ*64+(size_t)chunk*LC*64;
  const float*  xp=xib+(size_t)seq*LSEQ*64+(size_t)chunk*LC*64;
  const float4* bp=(const float4*)(bmb+(size_t)seq*LSEQ*16+(size_t)chunk*LC*16);
  float E[16];
  #pragma unroll
  for(int s=0;s<16;s++) E[s]=0.f;
  float Sdl=0.f;
  for(int i=0;i<LC;i++){
    float dl=dp[i*64+d], xv=xp[i*64+d];
    float4 b0=bp[i*4+0], b1=bp[i*4+1], b2=bp[i*4+2], b3=bp[i*4+3];
    float bb[16]={b0.x,b0.y,b0.z,b0.w, b1.x,b1.y,b1.z,b1.w,
                  b2.x,b2.y,b2.z,b2.w, b3.x,b3.y,b3.z,b3.w};
    float u=dl*xv; Sdl+=dl;
    #pragma unroll
    for(int s=0;s<16;s++){
      float dA=exp2f(dl*as[s]);
      E[s]=fmaf(dA,E[s],u*bb[s]);
    }
  }
  size_t o=(((size_t)seq*NC+chunk)*64+d)*16;
  float4* pp=(float4*)(pb+o); float4* ep=(float4*)(eb+o);
  #pragma unroll
  for(int q=0;q<4;q++){
    pp[q]=make_float4(exp2f(Sdl*as[q*4+0]),exp2f(Sdl*as[q*4+1]),
                      exp2f(Sdl*as[q*4+2]),exp2f(Sdl*as[q*4+3]));
    ep[q]=make_float4(E[q*4+0],E[q*4+1],E[q*4+2],E[q*4+3]);
  }
}

// ---------------- K3b: combine chunk summaries (p_hs aliases pb; read-before-write) ----------------
__global__ __launch_bounds__(1024) void k3b_combine(
  float* p_hs, const float* __restrict__ eb)
{
  const int seq=blockIdx.x, t=threadIdx.x;
  float h=0.f;
  for(int c=0;c<NC;c++){
    size_t o=((size_t)seq*NC+c)*1024+t;
    float p=p_hs[o], e=eb[o];
    p_hs[o]=h;                 // h-start for this chunk
    h=fmaf(p,h,e);
  }
}

// ---------------- K3c: rescan with h0 + fused gate. lane=d, s in registers ----------------
__global__ __launch_bounds__(256) void k3c_scan_y(
  const int* __restrict__ did, const float* __restrict__ A_log, const float* __restrict__ Dp,
  const float* __restrict__ xib, const float* __restrict__ dlb,
  const float* __restrict__ bmb, const float* __restrict__ cmb,
  float* zgb,                      // z in, gated y out (in-place, per-element read-then-write)
  const float* __restrict__ hsb)
{
  const int seq=blockIdx.y, j=seq>>2;
  const int wave=threadIdx.x>>6, d=threadIdx.x&63;
  const int chunk=blockIdx.x*CPB+wave;
  const int m=mixer_of(did,j);
  const float LOG2E=1.44269504f;
  float as[16];
  {
    const float4* ap=(const float4*)(A_log + (size_t)m*1024 + d*16);
    #pragma unroll
    for(int q=0;q<4;q++){ float4 v=ap[q];
      as[q*4+0]=-expf(v.x)*LOG2E; as[q*4+1]=-expf(v.y)*LOG2E;
      as[q*4+2]=-expf(v.z)*LOG2E; as[q*4+3]=-expf(v.w)*LOG2E; }
  }
  const float dpv = Dp[m*64+d];
  float h[16];
  {
    const float4* hp=(const float4*)(hsb + (((size_t)seq*NC+chunk)*64+d)*16);
    #pragma unroll
    for(int q=0;q<4;q++){ float4 v=hp[q];
      h[q*4+0]=v.x; h[q*4+1]=v.y; h[q*4+2]=v.z; h[q*4+3]=v.w; }
  }
  const float*  dp=dlb+(size_t)seq*LSEQ*64+(size_t)chunk*LC*64;
  const float*  xp=xib+(size_t)seq*LSEQ*64+(size_t)chunk*LC*64;
  const float4* bp=(const float4*)(bmb+(size_t)seq*LSEQ*16+(size_t)chunk*LC*16);
  const float4* cp=(const float4*)(cmb+(size_t)seq*LSEQ*16+(size_t)chunk*LC*16);
  float* zp = zgb+(size_t)seq*LSEQ*64+(size_t)chunk*LC*64;

  for(int i=0;i<LC;i++){
    float dl=dp[i*64+d], xv=xp[i*64+d];
    float zv=zp[i*64+d];
    float4 b0=bp[i*4+0], b1=bp[i*4+1], b2=bp[i*4+2], b3=bp[i*4+3];
    float4 c0=cp[i*4+0], c1=cp[i*4+1], c2=cp[i*4+2], c3=cp[i*4+3];
    float bb[16]={b0.x,b0.y,b0.z,b0.w, b1.x,b1.y,b1.z,b1.w,
                  b2.x,b2.y,b2.z,b2.w, b3.x,b3.y,b3.z,b3.w};
    float cc[16]={c0.x,c0.y,c0.z,c0.w, c1.x,c1.y,c1.z,c1.w,
                  c2.x,c2.y,c2.z,c2.w, c3.x,c3.y,c3.z,c3.w};
    float u=dl*xv;
    float y0=0.f,y1=0.f,y2=0.f,y3=0.f;
    #pragma unroll
    for(int s=0;s<16;s++){
      float dA=exp2f(dl*as[s]);
      h[s]=fmaf(dA,h[s],u*bb[s]);
      float hv=h[s]*cc[s];
      if((s&3)==0) y0+=hv; else if((s&3)==1) y1+=hv; else if((s&3)==2) y2+=hv; else y3+=hv;
    }
    float y=(y0+y1)+(y2+y3);
    float yg=(y + dpv*xv)*silu_f(zv);
    zp[i*64+d]=yg;
  }
}

// ---------------- K4: out_proj + skip. 64 l per block ----------------
__global__ __launch_bounds__(256) void k4_gate_outproj(
  const int* __restrict__ did, const float* __restrict__ out_w,
  const float* __restrict__ skipv, const float* __restrict__ ygb,
  const float* __restrict__ xnb, float* __restrict__ xmb)
{
  const int seq=blockIdx.y, j=seq>>2, p=seq&3, t=threadIdx.x;
  const int l0=blockIdx.x*64;
  const int m=mixer_of(did,j);
  __shared__ float s_yg[64][64];
  __shared__ float s_ow[32][65];
  for(int idx=t; idx<2048; idx+=256) s_ow[idx>>6][idx&63]=out_w[m*2048+idx];
  for(int it=0; it<16; ++it){
    int idx = t + it*256;
    int ll = idx>>6, dd = idx&63;
    s_yg[ll][dd]=ygb[(size_t)seq*LSEQ*64 + (size_t)(l0+ll)*64 + dd];
  }
  __syncthreads();
  const int o = t&31, grp = t>>5;
  const float sk = skipv[m];
  for(int ll=grp; ll<64; ll+=8){
    float acc=0.f;
    #pragma unroll
    for(int dd=0;dd<64;dd++) acc += s_yg[ll][dd]*s_ow[o][dd];
    size_t xidx=((size_t)j*LSEQ + l0+ll)*128 + p*32 + o;
    xmb[xidx]=acc + sk*xnb[xidx];
  }
}

// ---------------- K5: LN2 + proj, both experts, 16 l per block ----------------
__global__ __launch_bounds__(256) void k5_ln2_proj(
  const int* __restrict__ did, const float* __restrict__ ln_g, const float* __restrict__ ln_b,
  const float* __restrict__ proj_w, const float* __restrict__ proj_b,
  const float* __restrict__ xmb, float* __restrict__ out)
{
  const int b=blockIdx.y, l0=blockIdx.x*16, t=threadIdx.x;
  const int eh = t>>7, local = t&127;
  const int j = 2*b+eh;
  const int m = mixer_of(did, j);
  __shared__ float s_xn[2][16][132];
  __shared__ float s_comb[16][132];
  __shared__ float s_murs[2][16][2];

  for(int idx=local; idx<2048; idx+=128){
    int ll=idx>>7, c=idx&127;
    s_xn[eh][ll][c] = xmb[((size_t)j*LSEQ + l0+ll)*128 + c];
  }
  __syncthreads();
  {
    const int lane = t&63;
    const int g = lane&7, lw = lane>>3;
    const int ll = ((t>>6)&1)*8 + lw;
    float sum=0.f;
    #pragma unroll
    for(int k=0;k<16;k++) sum += s_xn[eh][ll][g*16+k];
    sum += __shfl_xor(sum,1); sum += __shfl_xor(sum,2); sum += __shfl_xor(sum,4);
    float mu = sum*(1.f/128.f);
    float vs=0.f;
    #pragma unroll
    for(int k=0;k<16;k++){ float dv=s_xn[eh][ll][g*16+k]-mu; vs+=dv*dv; }
    vs += __shfl_xor(vs,1); vs += __shfl_xor(vs,2); vs += __shfl_xor(vs,4);
    if(g==0){ s_murs[eh][ll][0]=mu; s_murs[eh][ll][1]=rsqrtf(vs*(1.f/128.f)+1e-5f); }
  }
  __syncthreads();
  for(int idx=local; idx<2048; idx+=128){
    int ll=idx>>7, c=idx&127;
    float xn=(s_xn[eh][ll][c]-s_murs[eh][ll][0])*s_murs[eh][ll][1]*ln_g[m*128+c]+ln_b[m*128+c];
    s_xn[eh][ll][c]=xn;
  }
  __syncthreads();
  float acc[16];
  #pragma unroll
  for(int ll=0;ll<16;ll++) acc[ll]=0.f;
  {
    const float4* pw4 = (const float4*)(proj_w + (size_t)m*16384 + (size_t)local*128);
    #pragma unroll 4
    for(int c4=0;c4<32;c4++){
      float4 w = pw4[c4];
      int c = c4*4;
      #pragma unroll
      for(int ll=0;ll<16;ll++){
        acc[ll] += w.x*s_xn[eh][ll][c] + w.y*s_xn[eh][ll][c+1]
                 + w.z*s_xn[eh][ll][c+2] + w.w*s_xn[eh][ll][c+3];
      }
    }
  }
  float pb_v = proj_b[m*128+local];
  if(eh==0){
    #pragma unroll
    for(int ll=0;ll<16;ll++) s_comb[ll][local]=acc[ll]+pb_v;
  }
  __syncthreads();
  if(eh==1){
    #pragma unroll
    for(int ll=0;ll<16;ll++) s_comb[ll][local]+=acc[ll]+pb_v;
  }
  __syncthreads();
  for(int idx=t; idx<2048; idx+=256){
    int o=idx>>4, ll=idx&15;
    out[((size_t)b*128+o)*LSEQ + l0+ll] = s_comb[ll][o];
  }
}

extern "C" void kernel_launch(void* const* d_in, const int* in_sizes, int n_in,
                              void* d_out, int out_size, void* d_ws, size_t ws_size,
                              hipStream_t stream) {
  const float* x      = (const float*)d_in[0];
  const int*   did    = (const int*)d_in[1];
  const float* ln_g   = (const float*)d_in[2];
  const float* ln_b   = (const float*)d_in[3];
  const float* in_w   = (const float*)d_in[4];
  const float* conv_w = (const float*)d_in[5];
  const float* conv_b = (const float*)d_in[6];
  const float* xp_w   = (const float*)d_in[7];
  const float* dt_w   = (const float*)d_in[8];
  const float* dt_b   = (const float*)d_in[9];
  const float* A_log  = (const float*)d_in[10];
  const float* Dp     = (const float*)d_in[11];
  const float* out_w  = (const float*)d_in[12];
  const float* proj_w = (const float*)d_in[13];
  const float* proj_b = (const float*)d_in[14];
  const float* skipv  = (const float*)d_in[15];
  float* out = (float*)d_out;
  float* ws  = (float*)d_ws;

  float* xnb = ws;                                   // NJ*L*128   (2.1M f)
  float* xzr = xnb + (size_t)NJ*LSEQ*128;            // NSEQ*L*64  (4.2M f) dead after k2
  float* zb  = xzr + (size_t)NSEQ*LSEQ*64;           // NSEQ*L*64  z; becomes gated y in k3c
  float* xib = zb  + (size_t)NSEQ*LSEQ*64;           // NSEQ*L*64
  float* dlb = xib + (size_t)NSEQ*LSEQ*64;           // NSEQ*L*64
  float* bmb = dlb + (size_t)NSEQ*LSEQ*64;           // NSEQ*L*16
  float* cmb = bmb + (size_t)NSEQ*LSEQ*16;           // NSEQ*L*16
  float* xmb = cmb + (size_t)NSEQ*LSEQ*16;           // NJ*L*128
  // scan summaries overlaid on dead xzr: pb (2.1M) + eb (2.1M) = 4.2M floats
  float* pb  = xzr;                                  // NSEQ*NC*1024, reused as hsb by k3b
  float* eb  = xzr + (size_t)NSEQ*NC*1024;
  float* hsb = pb;
  float* ygb = zb;                                   // k3c writes gated y in place of z

  hipLaunchKernelGGL(k1_ln_inproj, dim3(LSEQ/32,NJ), dim3(256), 0, stream,
                     x,did,ln_g,ln_b,in_w,xnb,xzr,zb);
  hipLaunchKernelGGL(k2_conv_xproj, dim3(LSEQ/64,NSEQ), dim3(256), 0, stream,
                     did,conv_w,conv_b,xp_w,dt_w,dt_b,xzr,xib,dlb,bmb,cmb);
  hipLaunchKernelGGL(k3a_scan_pe, dim3(NC/CPB,NSEQ), dim3(256), 0, stream,
                     did,A_log,xib,dlb,bmb,pb,eb);
  hipLaunchKernelGGL(k3b_combine, dim3(NSEQ), dim3(1024), 0, stream, pb,eb);
  hipLaunchKernelGGL(k3c_scan_y, dim3(NC/CPB,NSEQ), dim3(256), 0, stream,
                     did,A_log,Dp,xib,dlb,bmb,cmb,zb,hsb);
  hipLaunchKernelGGL(k4_gate_outproj, dim3(LSEQ/64,NSEQ), dim3(256), 0, stream,
                     did,out_w,skipv,ygb,xnb,xmb);
  hipLaunchKernelGGL(k5_ln2_proj, dim3(LSEQ/16,2), dim3(256), 0, stream,
                     did,ln_g,ln_b,proj_w,proj_b,xmb,out);
}

// Round 4
// 174.944 us; speedup vs baseline: 1.3021x; 1.3021x over previous
//
#include <hip/hip_runtime.h>
#include <math.h>

#define LSEQ 4096   // D*H*W = 16*16*16
#define CIN  128
#define DI   64     // d_inner
#define NS   16     // d_state
#define NP   4      // parts
#define NJ   4      // jobs = (b, mixer) pairs
#define NSEQ 16     // NJ * NP independent mamba sequences
#define NC   128    // scan chunks
#define LC   32     // chunk length (NC*LC = LSEQ)
#define CPB  4      // chunks (waves) per block in scan kernels

__device__ __forceinline__ int mixer_of(const int* did, int j){
  if((j&1)==0) return 0;
  int d = did[j>>1];
  return 1 + (d < 1 ? d : 1);
}
__device__ __forceinline__ float silu_f(float x){ return x/(1.f+expf(-x)); }

// ---------------- K1: LN1 + in_proj. 32 l per block, w rows in registers ----------------
__global__ __launch_bounds__(256) void k1_ln_inproj(
  const float* __restrict__ x, const int* __restrict__ did,
  const float* __restrict__ ln_g, const float* __restrict__ ln_b,
  const float* __restrict__ in_w,
  float* __restrict__ xnb, float* __restrict__ xzr, float* __restrict__ zb)
{
  const int j = blockIdx.y, b = j>>1, t = threadIdx.x;
  const int l0 = blockIdx.x*32;
  const int m = mixer_of(did, j);
  __shared__ float s_x[128][33];    // [c][ll]
  __shared__ float s_xn[32][132];   // [ll][c]  (132 = 4*33: rows 16B aligned)
  __shared__ float s_mu[32], s_rs[32];

  for(int idx=t; idx<4096; idx+=256){
    int c = idx>>5, ll = idx&31;
    s_x[c][ll] = x[((size_t)b*CIN+c)*LSEQ + l0+ll];
  }
  float wreg[32];
  {
    const float4* wp = (const float4*)(in_w + (size_t)m*4096 + (size_t)(t&127)*32);
    #pragma unroll
    for(int i=0;i<8;i++){
      float4 v = wp[i];
      wreg[i*4+0]=v.x; wreg[i*4+1]=v.y; wreg[i*4+2]=v.z; wreg[i*4+3]=v.w;
    }
  }
  __syncthreads();

  {
    const int wv = t>>6, lane = t&63;
    const int g = lane&7, lw = lane>>3;
    const int ll = wv*8+lw;
    float sum=0.f;
    #pragma unroll
    for(int k=0;k<16;k++) sum += s_x[g*16+k][ll];
    sum += __shfl_xor(sum,1); sum += __shfl_xor(sum,2); sum += __shfl_xor(sum,4);
    float mu = sum*(1.f/128.f);
    float vs=0.f;
    #pragma unroll
    for(int k=0;k<16;k++){ float dv = s_x[g*16+k][ll]-mu; vs += dv*dv; }
    vs += __shfl_xor(vs,1); vs += __shfl_xor(vs,2); vs += __shfl_xor(vs,4);
    if(g==0){ s_mu[ll]=mu; s_rs[ll]=rsqrtf(vs*(1.f/128.f)+1e-5f); }
  }
  __syncthreads();

  for(int idx=t; idx<4096; idx+=256){
    int ll = idx>>7, c = idx&127;
    float xn = (s_x[c][ll]-s_mu[ll])*s_rs[ll]*ln_g[m*128+c] + ln_b[m*128+c];
    s_xn[ll][c] = xn;
    xnb[((size_t)j*LSEQ + l0+ll)*128 + c] = xn;
  }
  __syncthreads();

  const int e = t&127, hh = t>>7;
  for(int ll=hh*16; ll<hh*16+16; ++ll){
    #pragma unroll
    for(int q=0;q<4;q++){
      const float4* xr4 = (const float4*)(&s_xn[ll][q*32]);
      float acc=0.f;
      #pragma unroll
      for(int k4=0;k4<8;k4++){
        float4 xv = xr4[k4];
        acc += xv.x*wreg[k4*4+0] + xv.y*wreg[k4*4+1]
             + xv.z*wreg[k4*4+2] + xv.w*wreg[k4*4+3];
      }
      size_t base = ((size_t)(j*NP+q)*LSEQ + l0+ll)*64;
      if(e<64) xzr[base+e]=acc; else zb[base+e-64]=acc;
    }
  }
}

// ---------- K2: conv + SiLU + x_proj + dt/softplus. 64 l per block. writes packed (dl,xi) ----------
__global__ __launch_bounds__(256) void k2_conv_xproj(
  const int* __restrict__ did,
  const float* __restrict__ conv_w, const float* __restrict__ conv_b,
  const float* __restrict__ xp_w, const float* __restrict__ dt_w, const float* __restrict__ dt_b,
  const float* __restrict__ xzr, float* __restrict__ dxb,
  float* __restrict__ bmb, float* __restrict__ cmb)
{
  const int seq = blockIdx.y, j = seq>>2, t = threadIdx.x;
  const int l0 = blockIdx.x*64;
  const int m = mixer_of(did, j);
  __shared__ float s_xz[67][64];
  __shared__ float s_xi[64][64];
  __shared__ float s_cwT[4][64];
  __shared__ float s_cb[64], s_dtw[128], s_dtb[64];
  __shared__ float s_dbc[64][2];

  for(int idx=t; idx<67*64; idx+=256){
    int row = idx>>6, d = idx&63, l = l0-3+row;
    s_xz[row][d] = (l>=0) ? xzr[((size_t)seq*LSEQ + l)*64 + d] : 0.f;
  }
  // x_proj weights in registers (row o, 64 wide), o = t&63, active o<34
  const int o = t&63, lg = t>>6;
  float xpw_r[64];
  if(o<34){
    const float4* wp = (const float4*)(xp_w + (size_t)m*2176 + (size_t)o*64);
    #pragma unroll
    for(int k4=0;k4<16;k4++){
      float4 v = wp[k4];
      xpw_r[k4*4+0]=v.x; xpw_r[k4*4+1]=v.y; xpw_r[k4*4+2]=v.z; xpw_r[k4*4+3]=v.w;
    }
  }
  { int k = t>>6, d = t&63; s_cwT[k][d] = conv_w[m*256 + d*4 + k]; }
  if(t<64){ s_cb[t]=conv_b[m*64+t]; s_dtb[t]=dt_b[m*64+t]; }
  if(t<128) s_dtw[t]=dt_w[m*128+t];
  __syncthreads();

  for(int it=0; it<16; ++it){
    int idx = t + it*256;
    int ll = idx>>6, d = idx&63;
    float xc = s_cb[d];
    #pragma unroll
    for(int k=0;k<4;k++) xc += s_xz[ll+k][d]*s_cwT[k][d];
    float xiv = silu_f(xc);
    s_xi[ll][d]=xiv;
    dxb[(((size_t)seq*LSEQ + l0+ll)*64 + d)*2 + 1] = xiv;
  }
  __syncthreads();

  for(int ll=lg; ll<64; ll+=4){
    if(o<34){
      const float4* xi4 = (const float4*)(&s_xi[ll][0]);
      float acc=0.f;
      #pragma unroll
      for(int k4=0;k4<16;k4++){
        float4 v = xi4[k4];
        acc += v.x*xpw_r[k4*4+0] + v.y*xpw_r[k4*4+1]
             + v.z*xpw_r[k4*4+2] + v.w*xpw_r[k4*4+3];
      }
      if(o<2) s_dbc[ll][o]=acc;
      else if(o<18) bmb[((size_t)seq*LSEQ + l0+ll)*16 + o-2]=acc;
      else          cmb[((size_t)seq*LSEQ + l0+ll)*16 + o-18]=acc;
    }
  }
  __syncthreads();

  for(int it=0; it<16; ++it){
    int idx = t + it*256;
    int ll = idx>>6, d = idx&63;
    float dtv = s_dbc[ll][0]*s_dtw[d*2] + s_dbc[ll][1]*s_dtw[d*2+1] + s_dtb[d];
    float dlv = dtv>20.f ? dtv : log1pf(expf(dtv));
    dxb[(((size_t)seq*LSEQ + l0+ll)*64 + d)*2 + 0] = dlv;
  }
}

// ---------------- K3a: per-chunk summaries. lane=d, s in regs, B in LDS, dx prefetched ----------------
__global__ __launch_bounds__(256) void k3a_scan_pe(
  const int* __restrict__ did, const float* __restrict__ A_log,
  const float* __restrict__ dxb, const float* __restrict__ bmb,
  float* __restrict__ pb, float* __restrict__ eb)
{
  const int seq=blockIdx.y, j=seq>>2, t=threadIdx.x;
  const int wave=t>>6, d=t&63;
  const int chunk=blockIdx.x*CPB+wave;
  const int l0=blockIdx.x*CPB*LC;
  const int m=mixer_of(did,j);
  __shared__ float s_b[CPB*LC*NS];   // 2048 floats
  {
    const float4* src=(const float4*)(bmb + ((size_t)seq*LSEQ + l0)*NS);
    float4* dst=(float4*)s_b;
    dst[t]=src[t]; dst[t+256]=src[t+256];
  }
  const float LOG2E=1.44269504f;
  float as[16];
  {
    const float4* ap=(const float4*)(A_log + (size_t)m*1024 + d*16);
    #pragma unroll
    for(int q=0;q<4;q++){ float4 v=ap[q];
      as[q*4+0]=-expf(v.x)*LOG2E; as[q*4+1]=-expf(v.y)*LOG2E;
      as[q*4+2]=-expf(v.z)*LOG2E; as[q*4+3]=-expf(v.w)*LOG2E; }
  }
  const float2* dxp=(const float2*)(dxb + ((size_t)seq*LSEQ + (size_t)chunk*LC)*128);
  float E[16];
  #pragma unroll
  for(int s=0;s<16;s++) E[s]=0.f;
  float Sdl=0.f;
  __syncthreads();

  float2 dxA=dxp[d], dxB=dxp[64+d];
  #define STEPA(i_, dx_) { \
    float dl=dx_.x, xv=dx_.y; float u=dl*xv; Sdl+=dl; \
    const float4* bq=(const float4*)(s_b + wave*(LC*NS) + (i_)*NS); \
    float4 b0=bq[0],b1=bq[1],b2=bq[2],b3=bq[3]; \
    float bb[16]={b0.x,b0.y,b0.z,b0.w, b1.x,b1.y,b1.z,b1.w, \
                  b2.x,b2.y,b2.z,b2.w, b3.x,b3.y,b3.z,b3.w}; \
    _Pragma("unroll") \
    for(int s=0;s<16;s++){ float dA=exp2f(dl*as[s]); E[s]=fmaf(dA,E[s],u*bb[s]); } }
  for(int ii=0;ii<LC;ii+=2){
    float2 dx=dxA; if(ii+2<LC) dxA=dxp[(ii+2)*64+d];
    STEPA(ii,dx);
    dx=dxB; if(ii+3<LC) dxB=dxp[(ii+3)*64+d];
    STEPA(ii+1,dx);
  }
  #undef STEPA
  size_t oo=(((size_t)seq*NC+chunk)*64+d)*16;
  float4* pp=(float4*)(pb+oo); float4* ep=(float4*)(eb+oo);
  #pragma unroll
  for(int q=0;q<4;q++){
    pp[q]=make_float4(exp2f(Sdl*as[q*4+0]),exp2f(Sdl*as[q*4+1]),
                      exp2f(Sdl*as[q*4+2]),exp2f(Sdl*as[q*4+3]));
    ep[q]=make_float4(E[q*4+0],E[q*4+1],E[q*4+2],E[q*4+3]);
  }
}

// ---------------- K3b: combine chunk summaries, batched prefetch; hs written in-place into p ----------------
__global__ __launch_bounds__(256) void k3b_combine(
  float* p_hs, const float* __restrict__ eb)
{
  const int seq=blockIdx.y, q=blockIdx.x, t=threadIdx.x;
  const size_t elem = (size_t)q*256+t;
  #define OFF(c_) (((size_t)seq*NC+(c_))*1024 + elem)
  float pA[16],eA[16],pB[16],eB[16];
  #pragma unroll
  for(int k=0;k<16;k++){ pA[k]=p_hs[OFF(k)]; eA[k]=eb[OFF(k)]; }
  float h=0.f;
  for(int bt=0; bt<8; bt+=2){
    if(bt+1<8){
      #pragma unroll
      for(int k=0;k<16;k++){ pB[k]=p_hs[OFF((bt+1)*16+k)]; eB[k]=eb[OFF((bt+1)*16+k)]; }
    }
    #pragma unroll
    for(int k=0;k<16;k++){ p_hs[OFF(bt*16+k)]=h; h=fmaf(pA[k],h,eA[k]); }
    if(bt+2<8){
      #pragma unroll
      for(int k=0;k<16;k++){ pA[k]=p_hs[OFF((bt+2)*16+k)]; eA[k]=eb[OFF((bt+2)*16+k)]; }
    }
    #pragma unroll
    for(int k=0;k<16;k++){ p_hs[OFF((bt+1)*16+k)]=h; h=fmaf(pB[k],h,eB[k]); }
  }
  #undef OFF
}

// ---------------- K3c: rescan with h0 + fused gate. B,C in LDS, dx/z prefetched ----------------
__global__ __launch_bounds__(256) void k3c_scan_y(
  const int* __restrict__ did, const float* __restrict__ A_log, const float* __restrict__ Dp,
  const float* __restrict__ dxb,
  const float* __restrict__ bmb, const float* __restrict__ cmb,
  float* zgb, const float* __restrict__ hsb)
{
  const int seq=blockIdx.y, j=seq>>2, t=threadIdx.x;
  const int wave=t>>6, d=t&63;
  const int chunk=blockIdx.x*CPB+wave;
  const int l0=blockIdx.x*CPB*LC;
  const int m=mixer_of(did,j);
  __shared__ float s_b[CPB*LC*NS];
  __shared__ float s_c[CPB*LC*NS];
  {
    const float4* bsrc=(const float4*)(bmb + ((size_t)seq*LSEQ + l0)*NS);
    const float4* csrc=(const float4*)(cmb + ((size_t)seq*LSEQ + l0)*NS);
    float4* bdst=(float4*)s_b; float4* cdst=(float4*)s_c;
    bdst[t]=bsrc[t]; bdst[t+256]=bsrc[t+256];
    cdst[t]=csrc[t]; cdst[t+256]=csrc[t+256];
  }
  const float LOG2E=1.44269504f;
  float as[16];
  {
    const float4* ap=(const float4*)(A_log + (size_t)m*1024 + d*16);
    #pragma unroll
    for(int q=0;q<4;q++){ float4 v=ap[q];
      as[q*4+0]=-expf(v.x)*LOG2E; as[q*4+1]=-expf(v.y)*LOG2E;
      as[q*4+2]=-expf(v.z)*LOG2E; as[q*4+3]=-expf(v.w)*LOG2E; }
  }
  const float dpv = Dp[m*64+d];
  float h[16];
  {
    const float4* hp=(const float4*)(hsb + (((size_t)seq*NC+chunk)*64+d)*16);
    #pragma unroll
    for(int q=0;q<4;q++){ float4 v=hp[q];
      h[q*4+0]=v.x; h[q*4+1]=v.y; h[q*4+2]=v.z; h[q*4+3]=v.w; }
  }
  const float2* dxp=(const float2*)(dxb + ((size_t)seq*LSEQ + (size_t)chunk*LC)*128);
  float* zp = zgb+(size_t)seq*LSEQ*64+(size_t)chunk*LC*64;
  __syncthreads();

  float2 dxA=dxp[d],    dxB=dxp[64+d];
  float  zA =zp[d],     zB =zp[64+d];
  #define STEPC(i_, dx_, zv_) { \
    float dl=dx_.x, xv=dx_.y; float u=dl*xv; \
    const float4* bq=(const float4*)(s_b + wave*(LC*NS) + (i_)*NS); \
    const float4* cq=(const float4*)(s_c + wave*(LC*NS) + (i_)*NS); \
    float4 b0=bq[0],b1=bq[1],b2=bq[2],b3=bq[3]; \
    float4 c0=cq[0],c1=cq[1],c2=cq[2],c3=cq[3]; \
    float bb[16]={b0.x,b0.y,b0.z,b0.w, b1.x,b1.y,b1.z,b1.w, \
                  b2.x,b2.y,b2.z,b2.w, b3.x,b3.y,b3.z,b3.w}; \
    float cc[16]={c0.x,c0.y,c0.z,c0.w, c1.x,c1.y,c1.z,c1.w, \
                  c2.x,c2.y,c2.z,c2.w, c3.x,c3.y,c3.z,c3.w}; \
    float y0=0.f,y1=0.f,y2=0.f,y3=0.f; \
    _Pragma("unroll") \
    for(int s=0;s<16;s++){ \
      float dA=exp2f(dl*as[s]); \
      h[s]=fmaf(dA,h[s],u*bb[s]); \
      float hv=h[s]*cc[s]; \
      if((s&3)==0) y0+=hv; else if((s&3)==1) y1+=hv; else if((s&3)==2) y2+=hv; else y3+=hv; \
    } \
    float y=(y0+y1)+(y2+y3); \
    zp[(i_)*64+d] = (y + dpv*xv)*silu_f(zv_); }
  for(int ii=0;ii<LC;ii+=2){
    float2 dx=dxA; float zv=zA;
    if(ii+2<LC){ dxA=dxp[(ii+2)*64+d]; zA=zp[(ii+2)*64+d]; }
    STEPC(ii,dx,zv);
    dx=dxB; zv=zB;
    if(ii+3<LC){ dxB=dxp[(ii+3)*64+d]; zB=zp[(ii+3)*64+d]; }
    STEPC(ii+1,dx,zv);
  }
  #undef STEPC
}

// ---------------- K4: out_proj + skip. 64 l per block ----------------
__global__ __launch_bounds__(256) void k4_gate_outproj(
  const int* __restrict__ did, const float* __restrict__ out_w,
  const float* __restrict__ skipv, const float* __restrict__ ygb,
  const float* __restrict__ xnb, float* __restrict__ xmb)
{
  const int seq=blockIdx.y, j=seq>>2, p=seq&3, t=threadIdx.x;
  const int l0=blockIdx.x*64;
  const int m=mixer_of(did,j);
  __shared__ float s_yg[64][64];
  __shared__ float s_ow[32][65];
  for(int idx=t; idx<2048; idx+=256) s_ow[idx>>6][idx&63]=out_w[m*2048+idx];
  for(int it=0; it<16; ++it){
    int idx = t + it*256;
    int ll = idx>>6, dd = idx&63;
    s_yg[ll][dd]=ygb[(size_t)seq*LSEQ*64 + (size_t)(l0+ll)*64 + dd];
  }
  __syncthreads();
  const int o = t&31, grp = t>>5;
  const float sk = skipv[m];
  for(int ll=grp; ll<64; ll+=8){
    float acc=0.f;
    #pragma unroll
    for(int dd=0;dd<64;dd++) acc += s_yg[ll][dd]*s_ow[o][dd];
    size_t xidx=((size_t)j*LSEQ + l0+ll)*128 + p*32 + o;
    xmb[xidx]=acc + sk*xnb[xidx];
  }
}

// ---------------- K5: LN2 + proj, both experts, 16 l per block ----------------
__global__ __launch_bounds__(256) void k5_ln2_proj(
  const int* __restrict__ did, const float* __restrict__ ln_g, const float* __restrict__ ln_b,
  const float* __restrict__ proj_w, const float* __restrict__ proj_b,
  const float* __restrict__ xmb, float* __restrict__ out)
{
  const int b=blockIdx.y, l0=blockIdx.x*16, t=threadIdx.x;
  const int eh = t>>7, local = t&127;
  const int j = 2*b+eh;
  const int m = mixer_of(did, j);
  __shared__ float s_xn[2][16][132];
  __shared__ float s_comb[16][132];
  __shared__ float s_murs[2][16][2];

  for(int idx=local; idx<2048; idx+=128){
    int ll=idx>>7, c=idx&127;
    s_xn[eh][ll][c] = xmb[((size_t)j*LSEQ + l0+ll)*128 + c];
  }
  __syncthreads();
  {
    const int lane = t&63;
    const int g = lane&7, lw = lane>>3;
    const int ll = ((t>>6)&1)*8 + lw;
    float sum=0.f;
    #pragma unroll
    for(int k=0;k<16;k++) sum += s_xn[eh][ll][g*16+k];
    sum += __shfl_xor(sum,1); sum += __shfl_xor(sum,2); sum += __shfl_xor(sum,4);
    float mu = sum*(1.f/128.f);
    float vs=0.f;
    #pragma unroll
    for(int k=0;k<16;k++){ float dv=s_xn[eh][ll][g*16+k]-mu; vs+=dv*dv; }
    vs += __shfl_xor(vs,1); vs += __shfl_xor(vs,2); vs += __shfl_xor(vs,4);
    if(g==0){ s_murs[eh][ll][0]=mu; s_murs[eh][ll][1]=rsqrtf(vs*(1.f/128.f)+1e-5f); }
  }
  __syncthreads();
  for(int idx=local; idx<2048; idx+=128){
    int ll=idx>>7, c=idx&127;
    float xn=(s_xn[eh][ll][c]-s_murs[eh][ll][0])*s_murs[eh][ll][1]*ln_g[m*128+c]+ln_b[m*128+c];
    s_xn[eh][ll][c]=xn;
  }
  __syncthreads();
  float acc[16];
  #pragma unroll
  for(int ll=0;ll<16;ll++) acc[ll]=0.f;
  {
    const float4* pw4 = (const float4*)(proj_w + (size_t)m*16384 + (size_t)local*128);
    #pragma unroll 4
    for(int c4=0;c4<32;c4++){
      float4 w = pw4[c4];
      int c = c4*4;
      #pragma unroll
      for(int ll=0;ll<16;ll++){
        acc[ll] += w.x*s_xn[eh][ll][c] + w.y*s_xn[eh][ll][c+1]
                 + w.z*s_xn[eh][ll][c+2] + w.w*s_xn[eh][ll][c+3];
      }
    }
  }
  float pb_v = proj_b[m*128+local];
  if(eh==0){
    #pragma unroll
    for(int ll=0;ll<16;ll++) s_comb[ll][local]=acc[ll]+pb_v;
  }
  __syncthreads();
  if(eh==1){
    #pragma unroll
    for(int ll=0;ll<16;ll++) s_comb[ll][local]+=acc[ll]+pb_v;
  }
  __syncthreads();
  for(int idx=t; idx<2048; idx+=256){
    int o=idx>>4, ll=idx&15;
    out[((size_t)b*128+o)*LSEQ + l0+ll] = s_comb[ll][o];
  }
}

extern "C" void kernel_launch(void* const* d_in, const int* in_sizes, int n_in,
                              void* d_out, int out_size, void* d_ws, size_t ws_size,
                              hipStream_t stream) {
  const float* x      = (const float*)d_in[0];
  const int*   did    = (const int*)d_in[1];
  const float* ln_g   = (const float*)d_in[2];
  const float* ln_b   = (const float*)d_in[3];
  const float* in_w   = (const float*)d_in[4];
  const float* conv_w = (const float*)d_in[5];
  const float* conv_b = (const float*)d_in[6];
  const float* xp_w   = (const float*)d_in[7];
  const float* dt_w   = (const float*)d_in[8];
  const float* dt_b   = (const float*)d_in[9];
  const float* A_log  = (const float*)d_in[10];
  const float* Dp     = (const float*)d_in[11];
  const float* out_w  = (const float*)d_in[12];
  const float* proj_w = (const float*)d_in[13];
  const float* proj_b = (const float*)d_in[14];
  const float* skipv  = (const float*)d_in[15];
  float* out = (float*)d_out;
  float* ws  = (float*)d_ws;

  float* xnb = ws;                                   // NJ*L*128   (2.10M f)
  float* xzr = xnb + (size_t)NJ*LSEQ*128;            // NSEQ*L*64  (4.19M f) dead after k2 -> pb,eb
  float* zb  = xzr + (size_t)NSEQ*LSEQ*64;           // NSEQ*L*64  z; becomes gated y in k3c
  float* dxb = zb  + (size_t)NSEQ*LSEQ*64;           // NSEQ*L*64*2 packed (dl,xi)
  float* bmb = dxb + (size_t)NSEQ*LSEQ*128;          // NSEQ*L*16
  float* cmb = bmb + (size_t)NSEQ*LSEQ*16;           // NSEQ*L*16
  float* xmb = cmb + (size_t)NSEQ*LSEQ*16;           // NJ*L*128
  float* pb  = xzr;                                  // NSEQ*NC*1024 = 2.10M; hs in-place
  float* eb  = xzr + (size_t)NSEQ*NC*1024;           // 2.10M (fits in xzr's 4.19M)
  float* hsb = pb;
  float* ygb = zb;

  hipLaunchKernelGGL(k1_ln_inproj, dim3(LSEQ/32,NJ), dim3(256), 0, stream,
                     x,did,ln_g,ln_b,in_w,xnb,xzr,zb);
  hipLaunchKernelGGL(k2_conv_xproj, dim3(LSEQ/64,NSEQ), dim3(256), 0, stream,
                     did,conv_w,conv_b,xp_w,dt_w,dt_b,xzr,dxb,bmb,cmb);
  hipLaunchKernelGGL(k3a_scan_pe, dim3(NC/CPB,NSEQ), dim3(256), 0, stream,
                     did,A_log,dxb,bmb,pb,eb);
  hipLaunchKernelGGL(k3b_combine, dim3(4,NSEQ), dim3(256), 0, stream, pb,eb);
  hipLaunchKernelGGL(k3c_scan_y, dim3(NC/CPB,NSEQ), dim3(256), 0, stream,
                     did,A_log,Dp,dxb,bmb,cmb,zb,hsb);
  hipLaunchKernelGGL(k4_gate_outproj, dim3(LSEQ/64,NSEQ), dim3(256), 0, stream,
                     did,out_w,skipv,ygb,xnb,xmb);
  hipLaunchKernelGGL(k5_ln2_proj, dim3(LSEQ/16,2), dim3(256), 0, stream,
                     did,ln_g,ln_b,proj_w,proj_b,xmb,out);
}

// Round 5
// 160.276 us; speedup vs baseline: 1.4213x; 1.0915x over previous
//
#include <hip/hip_runtime.h>
#include <math.h>

#define LSEQ 4096   // D*H*W = 16*16*16
#define CIN  128
#define DI   64     // d_inner
#define NS   16     // d_state
#define NP   4      // parts
#define NJ   4      // jobs = (b, mixer) pairs
#define NSEQ 16     // NJ * NP independent mamba sequences
#define NC   128    // scan chunks
#define LC   32     // chunk length (NC*LC = LSEQ)
#define CPB  4      // chunks (waves) per block in scan kernels

__device__ __forceinline__ int mixer_of(const int* did, int j){
  if((j&1)==0) return 0;
  int d = did[j>>1];
  return 1 + (d < 1 ? d : 1);
}
__device__ __forceinline__ float silu_f(float x){ return x/(1.f+expf(-x)); }

// ---------------- K1: LN1 + in_proj. 32 l per block, w rows in registers ----------------
__global__ __launch_bounds__(256) void k1_ln_inproj(
  const float* __restrict__ x, const int* __restrict__ did,
  const float* __restrict__ ln_g, const float* __restrict__ ln_b,
  const float* __restrict__ in_w,
  float* __restrict__ xnb, float* __restrict__ xzr, float* __restrict__ zb)
{
  const int j = blockIdx.y, b = j>>1, t = threadIdx.x;
  const int l0 = blockIdx.x*32;
  const int m = mixer_of(did, j);
  __shared__ float s_x[128][33];    // [c][ll]
  __shared__ float s_xn[32][132];   // [ll][c]  (132 = 4*33: rows 16B aligned)
  __shared__ float s_mu[32], s_rs[32];

  for(int idx=t; idx<4096; idx+=256){
    int c = idx>>5, ll = idx&31;
    s_x[c][ll] = x[((size_t)b*CIN+c)*LSEQ + l0+ll];
  }
  float wreg[32];
  {
    const float4* wp = (const float4*)(in_w + (size_t)m*4096 + (size_t)(t&127)*32);
    #pragma unroll
    for(int i=0;i<8;i++){
      float4 v = wp[i];
      wreg[i*4+0]=v.x; wreg[i*4+1]=v.y; wreg[i*4+2]=v.z; wreg[i*4+3]=v.w;
    }
  }
  __syncthreads();

  {
    const int wv = t>>6, lane = t&63;
    const int g = lane&7, lw = lane>>3;
    const int ll = wv*8+lw;
    float sum=0.f;
    #pragma unroll
    for(int k=0;k<16;k++) sum += s_x[g*16+k][ll];
    sum += __shfl_xor(sum,1); sum += __shfl_xor(sum,2); sum += __shfl_xor(sum,4);
    float mu = sum*(1.f/128.f);
    float vs=0.f;
    #pragma unroll
    for(int k=0;k<16;k++){ float dv = s_x[g*16+k][ll]-mu; vs += dv*dv; }
    vs += __shfl_xor(vs,1); vs += __shfl_xor(vs,2); vs += __shfl_xor(vs,4);
    if(g==0){ s_mu[ll]=mu; s_rs[ll]=rsqrtf(vs*(1.f/128.f)+1e-5f); }
  }
  __syncthreads();

  for(int idx=t; idx<4096; idx+=256){
    int ll = idx>>7, c = idx&127;
    float xn = (s_x[c][ll]-s_mu[ll])*s_rs[ll]*ln_g[m*128+c] + ln_b[m*128+c];
    s_xn[ll][c] = xn;
    xnb[((size_t)j*LSEQ + l0+ll)*128 + c] = xn;
  }
  __syncthreads();

  const int e = t&127, hh = t>>7;
  for(int ll=hh*16; ll<hh*16+16; ++ll){
    #pragma unroll
    for(int q=0;q<4;q++){
      const float4* xr4 = (const float4*)(&s_xn[ll][q*32]);
      float acc=0.f;
      #pragma unroll
      for(int k4=0;k4<8;k4++){
        float4 xv = xr4[k4];
        acc += xv.x*wreg[k4*4+0] + xv.y*wreg[k4*4+1]
             + xv.z*wreg[k4*4+2] + xv.w*wreg[k4*4+3];
      }
      size_t base = ((size_t)(j*NP+q)*LSEQ + l0+ll)*64;
      if(e<64) xzr[base+e]=acc; else zb[base+e-64]=acc;
    }
  }
}

// ---------- K2: conv + SiLU + x_proj + dt/softplus. 32 l per block, lean LDS, reg windows ----------
__global__ __launch_bounds__(256) void k2_conv_xproj(
  const int* __restrict__ did,
  const float* __restrict__ conv_w, const float* __restrict__ conv_b,
  const float* __restrict__ xp_w, const float* __restrict__ dt_w, const float* __restrict__ dt_b,
  const float* __restrict__ xzr, float* __restrict__ dxb,
  float* __restrict__ bmb, float* __restrict__ cmb)
{
  const int seq = blockIdx.y, j = seq>>2, t = threadIdx.x;
  const int l0 = blockIdx.x*32;
  const int m = mixer_of(did, j);
  const int d = t&63, r = t>>6;          // r = row-group (8 rows each)
  __shared__ float s_xi[32][64];
  __shared__ float s_dbc[32][2];
  __shared__ float s_cwT[4][64];
  __shared__ float s_cb[64], s_dtw[128], s_dtb[64];

  // conv input rows (register window, coalesced across d)
  float lz[11];
  #pragma unroll
  for(int i=0;i<11;i++){
    int l = l0 + r*8 - 3 + i;
    lz[i] = (l>=0) ? xzr[((size_t)seq*LSEQ + l)*64 + d] : 0.f;
  }
  { int k=t>>6, dd=t&63; s_cwT[k][dd]=conv_w[m*256+dd*4+k]; }
  if(t<64){ s_cb[t]=conv_b[m*64+t]; s_dtb[t]=dt_b[m*64+t]; }
  if(t<128) s_dtw[t]=dt_w[m*128+t];
  __syncthreads();

  // conv + silu -> s_xi
  {
    float cw0=s_cwT[0][d], cw1=s_cwT[1][d], cw2=s_cwT[2][d], cw3=s_cwT[3][d], cb=s_cb[d];
    #pragma unroll
    for(int i=0;i<8;i++){
      float xc = cb + lz[i]*cw0 + lz[i+1]*cw1 + lz[i+2]*cw2 + lz[i+3]*cw3;
      s_xi[r*8+i][d] = silu_f(xc);
    }
  }

  // x_proj weight row in registers (loaded post-conv to reduce peak pressure; issued pre-sync)
  float wreg[64];
  if(d<34){
    const float4* wp = (const float4*)(xp_w + (size_t)m*2176 + (size_t)d*64);
    #pragma unroll
    for(int k4=0;k4<16;k4++){
      float4 v = wp[k4];
      wreg[k4*4+0]=v.x; wreg[k4*4+1]=v.y; wreg[k4*4+2]=v.z; wreg[k4*4+3]=v.w;
    }
  }
  __syncthreads();

  // x_proj: lane = output o (o<34), rows r*8..r*8+7 as pairs, split accumulators
  if(d<34){
    #pragma unroll
    for(int ip=0; ip<4; ip++){
      int ll = r*8 + ip*2;
      const float4* xa=(const float4*)&s_xi[ll][0];
      const float4* xb=(const float4*)&s_xi[ll+1][0];
      float a0=0.f,a1=0.f,b0=0.f,b1=0.f;
      #pragma unroll
      for(int k=0;k<16;k+=2){
        float4 u=xa[k], u2=xa[k+1], v=xb[k], v2=xb[k+1];
        a0 += u.x *wreg[4*k+0]+u.y *wreg[4*k+1]+u.z *wreg[4*k+2]+u.w *wreg[4*k+3];
        a1 += u2.x*wreg[4*k+4]+u2.y*wreg[4*k+5]+u2.z*wreg[4*k+6]+u2.w*wreg[4*k+7];
        b0 += v.x *wreg[4*k+0]+v.y *wreg[4*k+1]+v.z *wreg[4*k+2]+v.w *wreg[4*k+3];
        b1 += v2.x*wreg[4*k+4]+v2.y*wreg[4*k+5]+v2.z*wreg[4*k+6]+v2.w*wreg[4*k+7];
      }
      float A=a0+a1, Bv=b0+b1;
      if(d<2){ s_dbc[ll][d]=A; s_dbc[ll+1][d]=Bv; }
      else if(d<18){
        bmb[((size_t)seq*LSEQ + l0+ll  )*16 + d-2]=A;
        bmb[((size_t)seq*LSEQ + l0+ll+1)*16 + d-2]=Bv;
      } else {
        cmb[((size_t)seq*LSEQ + l0+ll  )*16 + d-18]=A;
        cmb[((size_t)seq*LSEQ + l0+ll+1)*16 + d-18]=Bv;
      }
    }
  }
  __syncthreads();

  // dt proj + softplus + packed (dl, xi) coalesced float2 store
  {
    float w0=s_dtw[d*2], w1=s_dtw[d*2+1], bb=s_dtb[d];
    #pragma unroll
    for(int i=0;i<8;i++){
      int ll=r*8+i;
      float dtv = s_dbc[ll][0]*w0 + s_dbc[ll][1]*w1 + bb;
      float dlv = dtv>20.f ? dtv : log1pf(expf(dtv));
      float2 pk; pk.x=dlv; pk.y=s_xi[ll][d];
      *(float2*)(dxb + ((size_t)seq*LSEQ + l0+ll)*128 + d*2) = pk;
    }
  }
}

// ---------------- K3a: per-chunk summaries. lane=d, s in regs, B in LDS, dx prefetched ----------------
__global__ __launch_bounds__(256) void k3a_scan_pe(
  const int* __restrict__ did, const float* __restrict__ A_log,
  const float* __restrict__ dxb, const float* __restrict__ bmb,
  float* __restrict__ pb, float* __restrict__ eb)
{
  const int seq=blockIdx.y, j=seq>>2, t=threadIdx.x;
  const int wave=t>>6, d=t&63;
  const int chunk=blockIdx.x*CPB+wave;
  const int l0=blockIdx.x*CPB*LC;
  const int m=mixer_of(did,j);
  __shared__ float s_b[CPB*LC*NS];   // 2048 floats
  {
    const float4* src=(const float4*)(bmb + ((size_t)seq*LSEQ + l0)*NS);
    float4* dst=(float4*)s_b;
    dst[t]=src[t]; dst[t+256]=src[t+256];
  }
  const float LOG2E=1.44269504f;
  float as[16];
  {
    const float4* ap=(const float4*)(A_log + (size_t)m*1024 + d*16);
    #pragma unroll
    for(int q=0;q<4;q++){ float4 v=ap[q];
      as[q*4+0]=-expf(v.x)*LOG2E; as[q*4+1]=-expf(v.y)*LOG2E;
      as[q*4+2]=-expf(v.z)*LOG2E; as[q*4+3]=-expf(v.w)*LOG2E; }
  }
  const float2* dxp=(const float2*)(dxb + ((size_t)seq*LSEQ + (size_t)chunk*LC)*128);
  float E[16];
  #pragma unroll
  for(int s=0;s<16;s++) E[s]=0.f;
  float Sdl=0.f;
  __syncthreads();

  float2 dxA=dxp[d], dxB=dxp[64+d];
  #define STEPA(i_, dx_) { \
    float dl=dx_.x, xv=dx_.y; float u=dl*xv; Sdl+=dl; \
    const float4* bq=(const float4*)(s_b + wave*(LC*NS) + (i_)*NS); \
    float4 b0=bq[0],b1=bq[1],b2=bq[2],b3=bq[3]; \
    float bb[16]={b0.x,b0.y,b0.z,b0.w, b1.x,b1.y,b1.z,b1.w, \
                  b2.x,b2.y,b2.z,b2.w, b3.x,b3.y,b3.z,b3.w}; \
    _Pragma("unroll") \
    for(int s=0;s<16;s++){ float dA=exp2f(dl*as[s]); E[s]=fmaf(dA,E[s],u*bb[s]); } }
  for(int ii=0;ii<LC;ii+=2){
    float2 dx=dxA; if(ii+2<LC) dxA=dxp[(ii+2)*64+d];
    STEPA(ii,dx);
    dx=dxB; if(ii+3<LC) dxB=dxp[(ii+3)*64+d];
    STEPA(ii+1,dx);
  }
  #undef STEPA
  size_t oo=(((size_t)seq*NC+chunk)*64+d)*16;
  float4* pp=(float4*)(pb+oo); float4* ep=(float4*)(eb+oo);
  #pragma unroll
  for(int q=0;q<4;q++){
    pp[q]=make_float4(exp2f(Sdl*as[q*4+0]),exp2f(Sdl*as[q*4+1]),
                      exp2f(Sdl*as[q*4+2]),exp2f(Sdl*as[q*4+3]));
    ep[q]=make_float4(E[q*4+0],E[q*4+1],E[q*4+2],E[q*4+3]);
  }
}

// ---------------- K3b: combine chunk summaries, batched prefetch; hs written in-place into p ----------------
__global__ __launch_bounds__(256) void k3b_combine(
  float* p_hs, const float* __restrict__ eb)
{
  const int seq=blockIdx.y, q=blockIdx.x, t=threadIdx.x;
  const size_t elem = (size_t)q*256+t;
  #define OFF(c_) (((size_t)seq*NC+(c_))*1024 + elem)
  float pA[16],eA[16],pB[16],eB[16];
  #pragma unroll
  for(int k=0;k<16;k++){ pA[k]=p_hs[OFF(k)]; eA[k]=eb[OFF(k)]; }
  float h=0.f;
  for(int bt=0; bt<8; bt+=2){
    if(bt+1<8){
      #pragma unroll
      for(int k=0;k<16;k++){ pB[k]=p_hs[OFF((bt+1)*16+k)]; eB[k]=eb[OFF((bt+1)*16+k)]; }
    }
    #pragma unroll
    for(int k=0;k<16;k++){ p_hs[OFF(bt*16+k)]=h; h=fmaf(pA[k],h,eA[k]); }
    if(bt+2<8){
      #pragma unroll
      for(int k=0;k<16;k++){ pA[k]=p_hs[OFF((bt+2)*16+k)]; eA[k]=eb[OFF((bt+2)*16+k)]; }
    }
    #pragma unroll
    for(int k=0;k<16;k++){ p_hs[OFF((bt+1)*16+k)]=h; h=fmaf(pB[k],h,eB[k]); }
  }
  #undef OFF
}

// ---------------- K3c: rescan with h0 + fused gate. B,C in LDS, dx/z prefetched ----------------
__global__ __launch_bounds__(256) void k3c_scan_y(
  const int* __restrict__ did, const float* __restrict__ A_log, const float* __restrict__ Dp,
  const float* __restrict__ dxb,
  const float* __restrict__ bmb, const float* __restrict__ cmb,
  float* zgb, const float* __restrict__ hsb)
{
  const int seq=blockIdx.y, j=seq>>2, t=threadIdx.x;
  const int wave=t>>6, d=t&63;
  const int chunk=blockIdx.x*CPB+wave;
  const int l0=blockIdx.x*CPB*LC;
  const int m=mixer_of(did,j);
  __shared__ float s_b[CPB*LC*NS];
  __shared__ float s_c[CPB*LC*NS];
  {
    const float4* bsrc=(const float4*)(bmb + ((size_t)seq*LSEQ + l0)*NS);
    const float4* csrc=(const float4*)(cmb + ((size_t)seq*LSEQ + l0)*NS);
    float4* bdst=(float4*)s_b; float4* cdst=(float4*)s_c;
    bdst[t]=bsrc[t]; bdst[t+256]=bsrc[t+256];
    cdst[t]=csrc[t]; cdst[t+256]=csrc[t+256];
  }
  const float LOG2E=1.44269504f;
  float as[16];
  {
    const float4* ap=(const float4*)(A_log + (size_t)m*1024 + d*16);
    #pragma unroll
    for(int q=0;q<4;q++){ float4 v=ap[q];
      as[q*4+0]=-expf(v.x)*LOG2E; as[q*4+1]=-expf(v.y)*LOG2E;
      as[q*4+2]=-expf(v.z)*LOG2E; as[q*4+3]=-expf(v.w)*LOG2E; }
  }
  const float dpv = Dp[m*64+d];
  float h[16];
  {
    const float4* hp=(const float4*)(hsb + (((size_t)seq*NC+chunk)*64+d)*16);
    #pragma unroll
    for(int q=0;q<4;q++){ float4 v=hp[q];
      h[q*4+0]=v.x; h[q*4+1]=v.y; h[q*4+2]=v.z; h[q*4+3]=v.w; }
  }
  const float2* dxp=(const float2*)(dxb + ((size_t)seq*LSEQ + (size_t)chunk*LC)*128);
  float* zp = zgb+(size_t)seq*LSEQ*64+(size_t)chunk*LC*64;
  __syncthreads();

  float2 dxA=dxp[d],    dxB=dxp[64+d];
  float  zA =zp[d],     zB =zp[64+d];
  #define STEPC(i_, dx_, zv_) { \
    float dl=dx_.x, xv=dx_.y; float u=dl*xv; \
    const float4* bq=(const float4*)(s_b + wave*(LC*NS) + (i_)*NS); \
    const float4* cq=(const float4*)(s_c + wave*(LC*NS) + (i_)*NS); \
    float4 b0=bq[0],b1=bq[1],b2=bq[2],b3=bq[3]; \
    float4 c0=cq[0],c1=cq[1],c2=cq[2],c3=cq[3]; \
    float bb[16]={b0.x,b0.y,b0.z,b0.w, b1.x,b1.y,b1.z,b1.w, \
                  b2.x,b2.y,b2.z,b2.w, b3.x,b3.y,b3.z,b3.w}; \
    float cc[16]={c0.x,c0.y,c0.z,c0.w, c1.x,c1.y,c1.z,c1.w, \
                  c2.x,c2.y,c2.z,c2.w, c3.x,c3.y,c3.z,c3.w}; \
    float y0=0.f,y1=0.f,y2=0.f,y3=0.f; \
    _Pragma("unroll") \
    for(int s=0;s<16;s++){ \
      float dA=exp2f(dl*as[s]); \
      h[s]=fmaf(dA,h[s],u*bb[s]); \
      float hv=h[s]*cc[s]; \
      if((s&3)==0) y0+=hv; else if((s&3)==1) y1+=hv; else if((s&3)==2) y2+=hv; else y3+=hv; \
    } \
    float y=(y0+y1)+(y2+y3); \
    zp[(i_)*64+d] = (y + dpv*xv)*silu_f(zv_); }
  for(int ii=0;ii<LC;ii+=2){
    float2 dx=dxA; float zv=zA;
    if(ii+2<LC){ dxA=dxp[(ii+2)*64+d]; zA=zp[(ii+2)*64+d]; }
    STEPC(ii,dx,zv);
    dx=dxB; zv=zB;
    if(ii+3<LC){ dxB=dxp[(ii+3)*64+d]; zB=zp[(ii+3)*64+d]; }
    STEPC(ii+1,dx,zv);
  }
  #undef STEPC
}

// ---------------- K4: out_proj + skip. 64 l per block, out_w rows in registers ----------------
__global__ __launch_bounds__(256) void k4_gate_outproj(
  const int* __restrict__ did, const float* __restrict__ out_w,
  const float* __restrict__ skipv, const float* __restrict__ ygb,
  const float* __restrict__ xnb, float* __restrict__ xmb)
{
  const int seq=blockIdx.y, j=seq>>2, p=seq&3, t=threadIdx.x;
  const int l0=blockIdx.x*64;
  const int m=mixer_of(did,j);
  const int o=t&31, grp=t>>5;     // 8 groups x 8 rows
  __shared__ float s_yg[64][64];
  float wreg[64];
  {
    const float4* wp=(const float4*)(out_w + (size_t)m*2048 + (size_t)o*64);
    #pragma unroll
    for(int k4=0;k4<16;k4++){
      float4 v=wp[k4];
      wreg[k4*4+0]=v.x; wreg[k4*4+1]=v.y; wreg[k4*4+2]=v.z; wreg[k4*4+3]=v.w;
    }
  }
  {
    const float4* src=(const float4*)(ygb + (size_t)seq*LSEQ*64 + (size_t)l0*64);
    float4* dst=(float4*)s_yg;
    #pragma unroll
    for(int i=0;i<4;i++) dst[t + i*256] = src[t + i*256];
  }
  __syncthreads();
  const float sk = skipv[m];
  #pragma unroll
  for(int ip=0; ip<4; ip++){
    int ll = grp*8 + ip*2;
    const float4* xa=(const float4*)&s_yg[ll][0];
    const float4* xb=(const float4*)&s_yg[ll+1][0];
    float a0=0.f,a1=0.f,b0=0.f,b1=0.f;
    #pragma unroll
    for(int k=0;k<16;k+=2){
      float4 u=xa[k], u2=xa[k+1], v=xb[k], v2=xb[k+1];
      a0 += u.x *wreg[4*k+0]+u.y *wreg[4*k+1]+u.z *wreg[4*k+2]+u.w *wreg[4*k+3];
      a1 += u2.x*wreg[4*k+4]+u2.y*wreg[4*k+5]+u2.z*wreg[4*k+6]+u2.w*wreg[4*k+7];
      b0 += v.x *wreg[4*k+0]+v.y *wreg[4*k+1]+v.z *wreg[4*k+2]+v.w *wreg[4*k+3];
      b1 += v2.x*wreg[4*k+4]+v2.y*wreg[4*k+5]+v2.z*wreg[4*k+6]+v2.w*wreg[4*k+7];
    }
    size_t xidxA=((size_t)j*LSEQ + l0+ll)*128 + p*32 + o;
    xmb[xidxA]=(a0+a1) + sk*xnb[xidxA];
    size_t xidxB=xidxA + 128;
    xmb[xidxB]=(b0+b1) + sk*xnb[xidxB];
  }
}

// ---------------- K5: LN2 + proj, both experts, 16 l per block ----------------
__global__ __launch_bounds__(256) void k5_ln2_proj(
  const int* __restrict__ did, const float* __restrict__ ln_g, const float* __restrict__ ln_b,
  const float* __restrict__ proj_w, const float* __restrict__ proj_b,
  const float* __restrict__ xmb, float* __restrict__ out)
{
  const int b=blockIdx.y, l0=blockIdx.x*16, t=threadIdx.x;
  const int eh = t>>7, local = t&127;
  const int j = 2*b+eh;
  const int m = mixer_of(did, j);
  __shared__ float s_xn[2][16][132];
  __shared__ float s_comb[16][132];
  __shared__ float s_murs[2][16][2];

  for(int idx=local; idx<2048; idx+=128){
    int ll=idx>>7, c=idx&127;
    s_xn[eh][ll][c] = xmb[((size_t)j*LSEQ + l0+ll)*128 + c];
  }
  __syncthreads();
  {
    const int lane = t&63;
    const int g = lane&7, lw = lane>>3;
    const int ll = ((t>>6)&1)*8 + lw;
    float sum=0.f;
    #pragma unroll
    for(int k=0;k<16;k++) sum += s_xn[eh][ll][g*16+k];
    sum += __shfl_xor(sum,1); sum += __shfl_xor(sum,2); sum += __shfl_xor(sum,4);
    float mu = sum*(1.f/128.f);
    float vs=0.f;
    #pragma unroll
    for(int k=0;k<16;k++){ float dv=s_xn[eh][ll][g*16+k]-mu; vs+=dv*dv; }
    vs += __shfl_xor(vs,1); vs += __shfl_xor(vs,2); vs += __shfl_xor(vs,4);
    if(g==0){ s_murs[eh][ll][0]=mu; s_murs[eh][ll][1]=rsqrtf(vs*(1.f/128.f)+1e-5f); }
  }
  __syncthreads();
  for(int idx=local; idx<2048; idx+=128){
    int ll=idx>>7, c=idx&127;
    float xn=(s_xn[eh][ll][c]-s_murs[eh][ll][0])*s_murs[eh][ll][1]*ln_g[m*128+c]+ln_b[m*128+c];
    s_xn[eh][ll][c]=xn;
  }
  __syncthreads();
  float acc[16];
  #pragma unroll
  for(int ll=0;ll<16;ll++) acc[ll]=0.f;
  {
    const float4* pw4 = (const float4*)(proj_w + (size_t)m*16384 + (size_t)local*128);
    #pragma unroll 4
    for(int c4=0;c4<32;c4++){
      float4 w = pw4[c4];
      int c = c4*4;
      #pragma unroll
      for(int ll=0;ll<16;ll++){
        acc[ll] += w.x*s_xn[eh][ll][c] + w.y*s_xn[eh][ll][c+1]
                 + w.z*s_xn[eh][ll][c+2] + w.w*s_xn[eh][ll][c+3];
      }
    }
  }
  float pb_v = proj_b[m*128+local];
  if(eh==0){
    #pragma unroll
    for(int ll=0;ll<16;ll++) s_comb[ll][local]=acc[ll]+pb_v;
  }
  __syncthreads();
  if(eh==1){
    #pragma unroll
    for(int ll=0;ll<16;ll++) s_comb[ll][local]+=acc[ll]+pb_v;
  }
  __syncthreads();
  for(int idx=t; idx<2048; idx+=256){
    int o=idx>>4, ll=idx&15;
    out[((size_t)b*128+o)*LSEQ + l0+ll] = s_comb[ll][o];
  }
}

extern "C" void kernel_launch(void* const* d_in, const int* in_sizes, int n_in,
                              void* d_out, int out_size, void* d_ws, size_t ws_size,
                              hipStream_t stream) {
  const float* x      = (const float*)d_in[0];
  const int*   did    = (const int*)d_in[1];
  const float* ln_g   = (const float*)d_in[2];
  const float* ln_b   = (const float*)d_in[3];
  const float* in_w   = (const float*)d_in[4];
  const float* conv_w = (const float*)d_in[5];
  const float* conv_b = (const float*)d_in[6];
  const float* xp_w   = (const float*)d_in[7];
  const float* dt_w   = (const float*)d_in[8];
  const float* dt_b   = (const float*)d_in[9];
  const float* A_log  = (const float*)d_in[10];
  const float* Dp     = (const float*)d_in[11];
  const float* out_w  = (const float*)d_in[12];
  const float* proj_w = (const float*)d_in[13];
  const float* proj_b = (const float*)d_in[14];
  const float* skipv  = (const float*)d_in[15];
  float* out = (float*)d_out;
  float* ws  = (float*)d_ws;

  float* xnb = ws;                                   // NJ*L*128   (2.10M f)
  float* xzr = xnb + (size_t)NJ*LSEQ*128;            // NSEQ*L*64  (4.19M f) dead after k2 -> pb,eb
  float* zb  = xzr + (size_t)NSEQ*LSEQ*64;           // NSEQ*L*64  z; becomes gated y in k3c
  float* dxb = zb  + (size_t)NSEQ*LSEQ*64;           // NSEQ*L*64*2 packed (dl,xi)
  float* bmb = dxb + (size_t)NSEQ*LSEQ*128;          // NSEQ*L*16
  float* cmb = bmb + (size_t)NSEQ*LSEQ*16;           // NSEQ*L*16
  float* xmb = cmb + (size_t)NSEQ*LSEQ*16;           // NJ*L*128
  float* pb  = xzr;                                  // NSEQ*NC*1024 = 2.10M; hs in-place
  float* eb  = xzr + (size_t)NSEQ*NC*1024;           // 2.10M (fits in xzr's 4.19M)
  float* hsb = pb;
  float* ygb = zb;

  hipLaunchKernelGGL(k1_ln_inproj, dim3(LSEQ/32,NJ), dim3(256), 0, stream,
                     x,did,ln_g,ln_b,in_w,xnb,xzr,zb);
  hipLaunchKernelGGL(k2_conv_xproj, dim3(LSEQ/32,NSEQ), dim3(256), 0, stream,
                     did,conv_w,conv_b,xp_w,dt_w,dt_b,xzr,dxb,bmb,cmb);
  hipLaunchKernelGGL(k3a_scan_pe, dim3(NC/CPB,NSEQ), dim3(256), 0, stream,
                     did,A_log,dxb,bmb,pb,eb);
  hipLaunchKernelGGL(k3b_combine, dim3(4,NSEQ), dim3(256), 0, stream, pb,eb);
  hipLaunchKernelGGL(k3c_scan_y, dim3(NC/CPB,NSEQ), dim3(256), 0, stream,
                     did,A_log,Dp,dxb,bmb,cmb,zb,hsb);
  hipLaunchKernelGGL(k4_gate_outproj, dim3(LSEQ/64,NSEQ), dim3(256), 0, stream,
                     did,out_w,skipv,ygb,xnb,xmb);
  hipLaunchKernelGGL(k5_ln2_proj, dim3(LSEQ/16,2), dim3(256), 0, stream,
                     did,ln_g,ln_b,proj_w,proj_b,xmb,out);
}

// Round 6
// 153.697 us; speedup vs baseline: 1.4821x; 1.0428x over previous
//
#include <hip/hip_runtime.h>
#include <math.h>

#define LSEQ 4096   // D*H*W = 16*16*16
#define CIN  128
#define DI   64     // d_inner
#define NS   16     // d_state
#define NP   4      // parts
#define NJ   4      // jobs = (b, mixer) pairs
#define NSEQ 16     // NJ * NP independent mamba sequences
#define NC   128    // scan chunks
#define LC   32     // chunk length (NC*LC = LSEQ)
#define CPB  4      // chunks (waves) per block in scan kernels

__device__ __forceinline__ int mixer_of(const int* did, int j){
  if((j&1)==0) return 0;
  int d = did[j>>1];
  return 1 + (d < 1 ? d : 1);
}
__device__ __forceinline__ float silu_f(float x){ return x/(1.f+expf(-x)); }

// ---------------- K1: LN1 + in_proj. 32 l per block, w rows in registers ----------------
__global__ __launch_bounds__(256) void k1_ln_inproj(
  const float* __restrict__ x, const int* __restrict__ did,
  const float* __restrict__ ln_g, const float* __restrict__ ln_b,
  const float* __restrict__ in_w,
  float* __restrict__ xnb, float* __restrict__ xzr, float* __restrict__ zb)
{
  const int j = blockIdx.y, b = j>>1, t = threadIdx.x;
  const int l0 = blockIdx.x*32;
  const int m = mixer_of(did, j);
  __shared__ float s_x[128][33];    // [c][ll]
  __shared__ float s_xn[32][132];   // [ll][c]  (132 = 4*33: rows 16B aligned)
  __shared__ float s_mu[32], s_rs[32];

  for(int idx=t; idx<4096; idx+=256){
    int c = idx>>5, ll = idx&31;
    s_x[c][ll] = x[((size_t)b*CIN+c)*LSEQ + l0+ll];
  }
  float wreg[32];
  {
    const float4* wp = (const float4*)(in_w + (size_t)m*4096 + (size_t)(t&127)*32);
    #pragma unroll
    for(int i=0;i<8;i++){
      float4 v = wp[i];
      wreg[i*4+0]=v.x; wreg[i*4+1]=v.y; wreg[i*4+2]=v.z; wreg[i*4+3]=v.w;
    }
  }
  __syncthreads();

  {
    const int wv = t>>6, lane = t&63;
    const int g = lane&7, lw = lane>>3;
    const int ll = wv*8+lw;
    float sum=0.f;
    #pragma unroll
    for(int k=0;k<16;k++) sum += s_x[g*16+k][ll];
    sum += __shfl_xor(sum,1); sum += __shfl_xor(sum,2); sum += __shfl_xor(sum,4);
    float mu = sum*(1.f/128.f);
    float vs=0.f;
    #pragma unroll
    for(int k=0;k<16;k++){ float dv = s_x[g*16+k][ll]-mu; vs += dv*dv; }
    vs += __shfl_xor(vs,1); vs += __shfl_xor(vs,2); vs += __shfl_xor(vs,4);
    if(g==0){ s_mu[ll]=mu; s_rs[ll]=rsqrtf(vs*(1.f/128.f)+1e-5f); }
  }
  __syncthreads();

  for(int idx=t; idx<4096; idx+=256){
    int ll = idx>>7, c = idx&127;
    float xn = (s_x[c][ll]-s_mu[ll])*s_rs[ll]*ln_g[m*128+c] + ln_b[m*128+c];
    s_xn[ll][c] = xn;
    xnb[((size_t)j*LSEQ + l0+ll)*128 + c] = xn;
  }
  __syncthreads();

  const int e = t&127, hh = t>>7;
  for(int ll=hh*16; ll<hh*16+16; ++ll){
    #pragma unroll
    for(int q=0;q<4;q++){
      const float4* xr4 = (const float4*)(&s_xn[ll][q*32]);
      float acc=0.f;
      #pragma unroll
      for(int k4=0;k4<8;k4++){
        float4 xv = xr4[k4];
        acc += xv.x*wreg[k4*4+0] + xv.y*wreg[k4*4+1]
             + xv.z*wreg[k4*4+2] + xv.w*wreg[k4*4+3];
      }
      size_t base = ((size_t)(j*NP+q)*LSEQ + l0+ll)*64;
      if(e<64) xzr[base+e]=acc; else zb[base+e-64]=acc;
    }
  }
}

// ---------- K2: conv + SiLU + x_proj + dt/softplus. 32 l per block, lean LDS, reg windows ----------
__global__ __launch_bounds__(256) void k2_conv_xproj(
  const int* __restrict__ did,
  const float* __restrict__ conv_w, const float* __restrict__ conv_b,
  const float* __restrict__ xp_w, const float* __restrict__ dt_w, const float* __restrict__ dt_b,
  const float* __restrict__ xzr, float* __restrict__ dxb,
  float* __restrict__ bmb, float* __restrict__ cmb)
{
  const int seq = blockIdx.y, j = seq>>2, t = threadIdx.x;
  const int l0 = blockIdx.x*32;
  const int m = mixer_of(did, j);
  const int d = t&63, r = t>>6;          // r = row-group (8 rows each)
  __shared__ float s_xi[32][64];
  __shared__ float s_dbc[32][2];
  __shared__ float s_cwT[4][64];
  __shared__ float s_cb[64], s_dtw[128], s_dtb[64];

  float lz[11];
  #pragma unroll
  for(int i=0;i<11;i++){
    int l = l0 + r*8 - 3 + i;
    lz[i] = (l>=0) ? xzr[((size_t)seq*LSEQ + l)*64 + d] : 0.f;
  }
  { int k=t>>6, dd=t&63; s_cwT[k][dd]=conv_w[m*256+dd*4+k]; }
  if(t<64){ s_cb[t]=conv_b[m*64+t]; s_dtb[t]=dt_b[m*64+t]; }
  if(t<128) s_dtw[t]=dt_w[m*128+t];
  __syncthreads();

  {
    float cw0=s_cwT[0][d], cw1=s_cwT[1][d], cw2=s_cwT[2][d], cw3=s_cwT[3][d], cb=s_cb[d];
    #pragma unroll
    for(int i=0;i<8;i++){
      float xc = cb + lz[i]*cw0 + lz[i+1]*cw1 + lz[i+2]*cw2 + lz[i+3]*cw3;
      s_xi[r*8+i][d] = silu_f(xc);
    }
  }

  float wreg[64];
  if(d<34){
    const float4* wp = (const float4*)(xp_w + (size_t)m*2176 + (size_t)d*64);
    #pragma unroll
    for(int k4=0;k4<16;k4++){
      float4 v = wp[k4];
      wreg[k4*4+0]=v.x; wreg[k4*4+1]=v.y; wreg[k4*4+2]=v.z; wreg[k4*4+3]=v.w;
    }
  }
  __syncthreads();

  if(d<34){
    #pragma unroll
    for(int ip=0; ip<4; ip++){
      int ll = r*8 + ip*2;
      const float4* xa=(const float4*)&s_xi[ll][0];
      const float4* xb=(const float4*)&s_xi[ll+1][0];
      float a0=0.f,a1=0.f,b0=0.f,b1=0.f;
      #pragma unroll
      for(int k=0;k<16;k+=2){
        float4 u=xa[k], u2=xa[k+1], v=xb[k], v2=xb[k+1];
        a0 += u.x *wreg[4*k+0]+u.y *wreg[4*k+1]+u.z *wreg[4*k+2]+u.w *wreg[4*k+3];
        a1 += u2.x*wreg[4*k+4]+u2.y*wreg[4*k+5]+u2.z*wreg[4*k+6]+u2.w*wreg[4*k+7];
        b0 += v.x *wreg[4*k+0]+v.y *wreg[4*k+1]+v.z *wreg[4*k+2]+v.w *wreg[4*k+3];
        b1 += v2.x*wreg[4*k+4]+v2.y*wreg[4*k+5]+v2.z*wreg[4*k+6]+v2.w*wreg[4*k+7];
      }
      float A=a0+a1, Bv=b0+b1;
      if(d<2){ s_dbc[ll][d]=A; s_dbc[ll+1][d]=Bv; }
      else if(d<18){
        bmb[((size_t)seq*LSEQ + l0+ll  )*16 + d-2]=A;
        bmb[((size_t)seq*LSEQ + l0+ll+1)*16 + d-2]=Bv;
      } else {
        cmb[((size_t)seq*LSEQ + l0+ll  )*16 + d-18]=A;
        cmb[((size_t)seq*LSEQ + l0+ll+1)*16 + d-18]=Bv;
      }
    }
  }
  __syncthreads();

  {
    float w0=s_dtw[d*2], w1=s_dtw[d*2+1], bb=s_dtb[d];
    #pragma unroll
    for(int i=0;i<8;i++){
      int ll=r*8+i;
      float dtv = s_dbc[ll][0]*w0 + s_dbc[ll][1]*w1 + bb;
      float dlv = dtv>20.f ? dtv : log1pf(expf(dtv));
      float2 pk; pk.x=dlv; pk.y=s_xi[ll][d];
      *(float2*)(dxb + ((size_t)seq*LSEQ + l0+ll)*128 + d*2) = pk;
    }
  }
}

// ---------------- K3a: per-chunk summaries. lane=d, s in regs, B in LDS, 4-step batch prefetch ----------------
__global__ __launch_bounds__(256) void k3a_scan_pe(
  const int* __restrict__ did, const float* __restrict__ A_log,
  const float* __restrict__ dxb, const float* __restrict__ bmb,
  float* __restrict__ pb, float* __restrict__ eb)
{
  const int seq=blockIdx.y, j=seq>>2, t=threadIdx.x;
  const int wave=t>>6, d=t&63;
  const int chunk=blockIdx.x*CPB+wave;
  const int l0=blockIdx.x*CPB*LC;
  const int m=mixer_of(did,j);
  __shared__ float s_b[CPB*LC*NS];   // 2048 floats
  {
    const float4* src=(const float4*)(bmb + ((size_t)seq*LSEQ + l0)*NS);
    float4* dst=(float4*)s_b;
    dst[t]=src[t]; dst[t+256]=src[t+256];
  }
  const float LOG2E=1.44269504f;
  float as[16];
  {
    const float4* ap=(const float4*)(A_log + (size_t)m*1024 + d*16);
    #pragma unroll
    for(int q=0;q<4;q++){ float4 v=ap[q];
      as[q*4+0]=-expf(v.x)*LOG2E; as[q*4+1]=-expf(v.y)*LOG2E;
      as[q*4+2]=-expf(v.z)*LOG2E; as[q*4+3]=-expf(v.w)*LOG2E; }
  }
  const float2* dxp=(const float2*)(dxb + ((size_t)seq*LSEQ + (size_t)chunk*LC)*128);
  float E[16];
  #pragma unroll
  for(int s=0;s<16;s++) E[s]=0.f;
  float Sdl=0.f;
  __syncthreads();

  #define STEPA(i_, dx_) { \
    float dl=dx_.x, xv=dx_.y; float u=dl*xv; Sdl+=dl; \
    const float4* bq=(const float4*)(s_b + wave*(LC*NS) + (i_)*NS); \
    float4 b0=bq[0],b1=bq[1],b2=bq[2],b3=bq[3]; \
    float bb[16]={b0.x,b0.y,b0.z,b0.w, b1.x,b1.y,b1.z,b1.w, \
                  b2.x,b2.y,b2.z,b2.w, b3.x,b3.y,b3.z,b3.w}; \
    _Pragma("unroll") \
    for(int s=0;s<16;s++){ float dA=exp2f(dl*as[s]); E[s]=fmaf(dA,E[s],u*bb[s]); } }

  float2 dxw[4];
  #pragma unroll
  for(int k=0;k<4;k++) dxw[k]=dxp[k*64+d];
  for(int ii=0;ii<LC;ii+=4){
    float2 c0=dxw[0],c1=dxw[1],c2=dxw[2],c3=dxw[3];
    if(ii+4<LC){
      #pragma unroll
      for(int k=0;k<4;k++) dxw[k]=dxp[(ii+4+k)*64+d];
    }
    STEPA(ii+0,c0); STEPA(ii+1,c1); STEPA(ii+2,c2); STEPA(ii+3,c3);
  }
  #undef STEPA
  size_t oo=(((size_t)seq*NC+chunk)*64+d)*16;
  float4* pp=(float4*)(pb+oo); float4* ep=(float4*)(eb+oo);
  #pragma unroll
  for(int q=0;q<4;q++){
    pp[q]=make_float4(exp2f(Sdl*as[q*4+0]),exp2f(Sdl*as[q*4+1]),
                      exp2f(Sdl*as[q*4+2]),exp2f(Sdl*as[q*4+3]));
    ep[q]=make_float4(E[q*4+0],E[q*4+1],E[q*4+2],E[q*4+3]);
  }
}

// ---------------- K3b: combine chunk summaries, batched prefetch; hs written in-place into p ----------------
__global__ __launch_bounds__(256) void k3b_combine(
  float* p_hs, const float* __restrict__ eb)
{
  const int seq=blockIdx.y, q=blockIdx.x, t=threadIdx.x;
  const size_t elem = (size_t)q*256+t;
  #define OFF(c_) (((size_t)seq*NC+(c_))*1024 + elem)
  float pA[16],eA[16],pB[16],eB[16];
  #pragma unroll
  for(int k=0;k<16;k++){ pA[k]=p_hs[OFF(k)]; eA[k]=eb[OFF(k)]; }
  float h=0.f;
  for(int bt=0; bt<8; bt+=2){
    if(bt+1<8){
      #pragma unroll
      for(int k=0;k<16;k++){ pB[k]=p_hs[OFF((bt+1)*16+k)]; eB[k]=eb[OFF((bt+1)*16+k)]; }
    }
    #pragma unroll
    for(int k=0;k<16;k++){ p_hs[OFF(bt*16+k)]=h; h=fmaf(pA[k],h,eA[k]); }
    if(bt+2<8){
      #pragma unroll
      for(int k=0;k<16;k++){ pA[k]=p_hs[OFF((bt+2)*16+k)]; eA[k]=eb[OFF((bt+2)*16+k)]; }
    }
    #pragma unroll
    for(int k=0;k<16;k++){ p_hs[OFF((bt+1)*16+k)]=h; h=fmaf(pB[k],h,eB[k]); }
  }
  #undef OFF
}

// -------- K3C4: rescan + gate + out_proj + skip, fused. yg staged in LDS, never hits HBM --------
__global__ __launch_bounds__(256) void k3c4_scan_outproj(
  const int* __restrict__ did, const float* __restrict__ A_log, const float* __restrict__ Dp,
  const float* __restrict__ dxb,
  const float* __restrict__ bmb, const float* __restrict__ cmb,
  const float* __restrict__ zb, const float* __restrict__ hsb,
  const float* __restrict__ out_w, const float* __restrict__ skipv,
  const float* __restrict__ xnb, float* __restrict__ xmb)
{
  const int seq=blockIdx.y, j=seq>>2, p=seq&3, t=threadIdx.x;
  const int wave=t>>6, d=t&63;
  const int chunk=blockIdx.x*CPB+wave;
  const int l0=blockIdx.x*CPB*LC;          // 128 l per block
  const int m=mixer_of(did,j);
  __shared__ float s_b[CPB*LC*NS];         // 8KB
  __shared__ float s_c[CPB*LC*NS];         // 8KB
  __shared__ float s_yg[CPB*LC][68];       // 34.8KB, rows 16B-aligned, bank-staggered
  {
    const float4* bsrc=(const float4*)(bmb + ((size_t)seq*LSEQ + l0)*NS);
    const float4* csrc=(const float4*)(cmb + ((size_t)seq*LSEQ + l0)*NS);
    float4* bdst=(float4*)s_b; float4* cdst=(float4*)s_c;
    bdst[t]=bsrc[t]; bdst[t+256]=bsrc[t+256];
    cdst[t]=csrc[t]; cdst[t+256]=csrc[t+256];
  }
  const float LOG2E=1.44269504f;
  float as[16];
  {
    const float4* ap=(const float4*)(A_log + (size_t)m*1024 + d*16);
    #pragma unroll
    for(int q=0;q<4;q++){ float4 v=ap[q];
      as[q*4+0]=-expf(v.x)*LOG2E; as[q*4+1]=-expf(v.y)*LOG2E;
      as[q*4+2]=-expf(v.z)*LOG2E; as[q*4+3]=-expf(v.w)*LOG2E; }
  }
  const float dpv = Dp[m*64+d];
  float h[16];
  {
    const float4* hp=(const float4*)(hsb + (((size_t)seq*NC+chunk)*64+d)*16);
    #pragma unroll
    for(int q=0;q<4;q++){ float4 v=hp[q];
      h[q*4+0]=v.x; h[q*4+1]=v.y; h[q*4+2]=v.z; h[q*4+3]=v.w; }
  }
  const float2* dxp=(const float2*)(dxb + ((size_t)seq*LSEQ + (size_t)chunk*LC)*128);
  const float* zp = zb + (size_t)seq*LSEQ*64 + (size_t)chunk*LC*64;
  __syncthreads();

  #define STEPC(i_, dx_, zv_) { \
    float dl=dx_.x, xv=dx_.y; float u=dl*xv; \
    const float4* bq=(const float4*)(s_b + wave*(LC*NS) + (i_)*NS); \
    const float4* cq=(const float4*)(s_c + wave*(LC*NS) + (i_)*NS); \
    float4 b0=bq[0],b1=bq[1],b2=bq[2],b3=bq[3]; \
    float4 c0=cq[0],c1=cq[1],c2=cq[2],c3=cq[3]; \
    float bb[16]={b0.x,b0.y,b0.z,b0.w, b1.x,b1.y,b1.z,b1.w, \
                  b2.x,b2.y,b2.z,b2.w, b3.x,b3.y,b3.z,b3.w}; \
    float cc[16]={c0.x,c0.y,c0.z,c0.w, c1.x,c1.y,c1.z,c1.w, \
                  c2.x,c2.y,c2.z,c2.w, c3.x,c3.y,c3.z,c3.w}; \
    float y0=0.f,y1=0.f,y2=0.f,y3=0.f; \
    _Pragma("unroll") \
    for(int s=0;s<16;s++){ \
      float dA=exp2f(dl*as[s]); \
      h[s]=fmaf(dA,h[s],u*bb[s]); \
      float hv=h[s]*cc[s]; \
      if((s&3)==0) y0+=hv; else if((s&3)==1) y1+=hv; else if((s&3)==2) y2+=hv; else y3+=hv; \
    } \
    float y=(y0+y1)+(y2+y3); \
    s_yg[wave*LC + (i_)][d] = (y + dpv*xv)*silu_f(zv_); }

  float2 dxw[4]; float zw[4];
  #pragma unroll
  for(int k=0;k<4;k++){ dxw[k]=dxp[k*64+d]; zw[k]=zp[k*64+d]; }
  for(int ii=0;ii<LC;ii+=4){
    float2 c0=dxw[0],c1=dxw[1],c2=dxw[2],c3=dxw[3];
    float  z0=zw[0], z1=zw[1], z2=zw[2], z3=zw[3];
    if(ii+4<LC){
      #pragma unroll
      for(int k=0;k<4;k++){ dxw[k]=dxp[(ii+4+k)*64+d]; zw[k]=zp[(ii+4+k)*64+d]; }
    }
    STEPC(ii+0,c0,z0); STEPC(ii+1,c1,z1); STEPC(ii+2,c2,z2); STEPC(ii+3,c3,z3);
  }
  #undef STEPC

  // ---- epilogue: out_proj(32x64) + skip over this block's 128 l ----
  const int o=t&31, grp=t>>5;
  float wreg[64];
  {
    const float4* wp=(const float4*)(out_w + (size_t)m*2048 + (size_t)o*64);
    #pragma unroll
    for(int k4=0;k4<16;k4++){
      float4 v=wp[k4];
      wreg[k4*4+0]=v.x; wreg[k4*4+1]=v.y; wreg[k4*4+2]=v.z; wreg[k4*4+3]=v.w;
    }
  }
  const float sk=skipv[m];
  __syncthreads();
  for(int ll=grp; ll<CPB*LC; ll+=8){
    const float4* ya=(const float4*)&s_yg[ll][0];
    float a0=0.f,a1=0.f;
    #pragma unroll
    for(int k=0;k<16;k+=2){
      float4 u=ya[k], u2=ya[k+1];
      a0 += u.x *wreg[4*k+0]+u.y *wreg[4*k+1]+u.z *wreg[4*k+2]+u.w *wreg[4*k+3];
      a1 += u2.x*wreg[4*k+4]+u2.y*wreg[4*k+5]+u2.z*wreg[4*k+6]+u2.w*wreg[4*k+7];
    }
    size_t xidx=((size_t)j*LSEQ + l0+ll)*128 + p*32 + o;
    xmb[xidx]=(a0+a1) + sk*xnb[xidx];
  }
}

// ---------------- K5: LN2 + proj, both experts, 16 l per block ----------------
__global__ __launch_bounds__(256) void k5_ln2_proj(
  const int* __restrict__ did, const float* __restrict__ ln_g, const float* __restrict__ ln_b,
  const float* __restrict__ proj_w, const float* __restrict__ proj_b,
  const float* __restrict__ xmb, float* __restrict__ out)
{
  const int b=blockIdx.y, l0=blockIdx.x*16, t=threadIdx.x;
  const int eh = t>>7, local = t&127;
  const int j = 2*b+eh;
  const int m = mixer_of(did, j);
  __shared__ float s_xn[2][16][132];
  __shared__ float s_comb[16][132];
  __shared__ float s_murs[2][16][2];

  for(int idx=local; idx<2048; idx+=128){
    int ll=idx>>7, c=idx&127;
    s_xn[eh][ll][c] = xmb[((size_t)j*LSEQ + l0+ll)*128 + c];
  }
  __syncthreads();
  {
    const int lane = t&63;
    const int g = lane&7, lw = lane>>3;
    const int ll = ((t>>6)&1)*8 + lw;
    float sum=0.f;
    #pragma unroll
    for(int k=0;k<16;k++) sum += s_xn[eh][ll][g*16+k];
    sum += __shfl_xor(sum,1); sum += __shfl_xor(sum,2); sum += __shfl_xor(sum,4);
    float mu = sum*(1.f/128.f);
    float vs=0.f;
    #pragma unroll
    for(int k=0;k<16;k++){ float dv=s_xn[eh][ll][g*16+k]-mu; vs+=dv*dv; }
    vs += __shfl_xor(vs,1); vs += __shfl_xor(vs,2); vs += __shfl_xor(vs,4);
    if(g==0){ s_murs[eh][ll][0]=mu; s_murs[eh][ll][1]=rsqrtf(vs*(1.f/128.f)+1e-5f); }
  }
  __syncthreads();
  for(int idx=local; idx<2048; idx+=128){
    int ll=idx>>7, c=idx&127;
    float xn=(s_xn[eh][ll][c]-s_murs[eh][ll][0])*s_murs[eh][ll][1]*ln_g[m*128+c]+ln_b[m*128+c];
    s_xn[eh][ll][c]=xn;
  }
  __syncthreads();
  float acc[16];
  #pragma unroll
  for(int ll=0;ll<16;ll++) acc[ll]=0.f;
  {
    const float4* pw4 = (const float4*)(proj_w + (size_t)m*16384 + (size_t)local*128);
    #pragma unroll 4
    for(int c4=0;c4<32;c4++){
      float4 w = pw4[c4];
      int c = c4*4;
      #pragma unroll
      for(int ll=0;ll<16;ll++){
        acc[ll] += w.x*s_xn[eh][ll][c] + w.y*s_xn[eh][ll][c+1]
                 + w.z*s_xn[eh][ll][c+2] + w.w*s_xn[eh][ll][c+3];
      }
    }
  }
  float pb_v = proj_b[m*128+local];
  if(eh==0){
    #pragma unroll
    for(int ll=0;ll<16;ll++) s_comb[ll][local]=acc[ll]+pb_v;
  }
  __syncthreads();
  if(eh==1){
    #pragma unroll
    for(int ll=0;ll<16;ll++) s_comb[ll][local]+=acc[ll]+pb_v;
  }
  __syncthreads();
  for(int idx=t; idx<2048; idx+=256){
    int o=idx>>4, ll=idx&15;
    out[((size_t)b*128+o)*LSEQ + l0+ll] = s_comb[ll][o];
  }
}

extern "C" void kernel_launch(void* const* d_in, const int* in_sizes, int n_in,
                              void* d_out, int out_size, void* d_ws, size_t ws_size,
                              hipStream_t stream) {
  const float* x      = (const float*)d_in[0];
  const int*   did    = (const int*)d_in[1];
  const float* ln_g   = (const float*)d_in[2];
  const float* ln_b   = (const float*)d_in[3];
  const float* in_w   = (const float*)d_in[4];
  const float* conv_w = (const float*)d_in[5];
  const float* conv_b = (const float*)d_in[6];
  const float* xp_w   = (const float*)d_in[7];
  const float* dt_w   = (const float*)d_in[8];
  const float* dt_b   = (const float*)d_in[9];
  const float* A_log  = (const float*)d_in[10];
  const float* Dp     = (const float*)d_in[11];
  const float* out_w  = (const float*)d_in[12];
  const float* proj_w = (const float*)d_in[13];
  const float* proj_b = (const float*)d_in[14];
  const float* skipv  = (const float*)d_in[15];
  float* out = (float*)d_out;
  float* ws  = (float*)d_ws;

  float* xnb = ws;                                   // NJ*L*128   (2.10M f)
  float* xzr = xnb + (size_t)NJ*LSEQ*128;            // NSEQ*L*64  (4.19M f) dead after k2 -> pb,eb
  float* zb  = xzr + (size_t)NSEQ*LSEQ*64;           // NSEQ*L*64  z (read-only after k1)
  float* dxb = zb  + (size_t)NSEQ*LSEQ*64;           // NSEQ*L*64*2 packed (dl,xi)
  float* bmb = dxb + (size_t)NSEQ*LSEQ*128;          // NSEQ*L*16
  float* cmb = bmb + (size_t)NSEQ*LSEQ*16;           // NSEQ*L*16
  float* xmb = cmb + (size_t)NSEQ*LSEQ*16;           // NJ*L*128
  float* pb  = xzr;                                  // NSEQ*NC*1024 = 2.10M; hs in-place
  float* eb  = xzr + (size_t)NSEQ*NC*1024;           // 2.10M (fits in xzr's 4.19M)
  float* hsb = pb;

  hipLaunchKernelGGL(k1_ln_inproj, dim3(LSEQ/32,NJ), dim3(256), 0, stream,
                     x,did,ln_g,ln_b,in_w,xnb,xzr,zb);
  hipLaunchKernelGGL(k2_conv_xproj, dim3(LSEQ/32,NSEQ), dim3(256), 0, stream,
                     did,conv_w,conv_b,xp_w,dt_w,dt_b,xzr,dxb,bmb,cmb);
  hipLaunchKernelGGL(k3a_scan_pe, dim3(NC/CPB,NSEQ), dim3(256), 0, stream,
                     did,A_log,dxb,bmb,pb,eb);
  hipLaunchKernelGGL(k3b_combine, dim3(4,NSEQ), dim3(256), 0, stream, pb,eb);
  hipLaunchKernelGGL(k3c4_scan_outproj, dim3(NC/CPB,NSEQ), dim3(256), 0, stream,
                     did,A_log,Dp,dxb,bmb,cmb,zb,hsb,out_w,skipv,xnb,xmb);
  hipLaunchKernelGGL(k5_ln2_proj, dim3(LSEQ/16,2), dim3(256), 0, stream,
                     did,ln_g,ln_b,proj_w,proj_b,xmb,out);
}

// Round 7
// 138.969 us; speedup vs baseline: 1.6392x; 1.1060x over previous
//
#include <hip/hip_runtime.h>
#include <math.h>

#define LSEQ 4096   // D*H*W = 16*16*16
#define CIN  128
#define DI   64     // d_inner
#define NS   16     // d_state
#define NP   4      // parts
#define NJ   4      // jobs = (b, mixer) pairs
#define NSEQ 16     // NJ * NP independent mamba sequences
#define NC   128    // scan chunks
#define LC   32     // chunk length (NC*LC = LSEQ)
#define LOG2E 1.44269504f

__device__ __forceinline__ int mixer_of(const int* did, int j){
  if((j&1)==0) return 0;
  int d = did[j>>1];
  return 1 + (d < 1 ? d : 1);
}
__device__ __forceinline__ float silu_f(float x){ return x/(1.f+expf(-x)); }

// ---------------- K1: LN1 + in_proj. 32 l per block, w rows in registers ----------------
__global__ __launch_bounds__(256) void k1_ln_inproj(
  const float* __restrict__ x, const int* __restrict__ did,
  const float* __restrict__ ln_g, const float* __restrict__ ln_b,
  const float* __restrict__ in_w,
  float* __restrict__ xnb, float* __restrict__ xzr, float* __restrict__ zb)
{
  const int j = blockIdx.y, b = j>>1, t = threadIdx.x;
  const int l0 = blockIdx.x*32;
  const int m = mixer_of(did, j);
  __shared__ float s_x[128][33];    // [c][ll]
  __shared__ float s_xn[32][132];   // [ll][c]  (132 = 4*33: rows 16B aligned)
  __shared__ float s_mu[32], s_rs[32];

  for(int idx=t; idx<4096; idx+=256){
    int c = idx>>5, ll = idx&31;
    s_x[c][ll] = x[((size_t)b*CIN+c)*LSEQ + l0+ll];
  }
  float wreg[32];
  {
    const float4* wp = (const float4*)(in_w + (size_t)m*4096 + (size_t)(t&127)*32);
    #pragma unroll
    for(int i=0;i<8;i++){
      float4 v = wp[i];
      wreg[i*4+0]=v.x; wreg[i*4+1]=v.y; wreg[i*4+2]=v.z; wreg[i*4+3]=v.w;
    }
  }
  __syncthreads();

  {
    const int wv = t>>6, lane = t&63;
    const int g = lane&7, lw = lane>>3;
    const int ll = wv*8+lw;
    float sum=0.f;
    #pragma unroll
    for(int k=0;k<16;k++) sum += s_x[g*16+k][ll];
    sum += __shfl_xor(sum,1); sum += __shfl_xor(sum,2); sum += __shfl_xor(sum,4);
    float mu = sum*(1.f/128.f);
    float vs=0.f;
    #pragma unroll
    for(int k=0;k<16;k++){ float dv = s_x[g*16+k][ll]-mu; vs += dv*dv; }
    vs += __shfl_xor(vs,1); vs += __shfl_xor(vs,2); vs += __shfl_xor(vs,4);
    if(g==0){ s_mu[ll]=mu; s_rs[ll]=rsqrtf(vs*(1.f/128.f)+1e-5f); }
  }
  __syncthreads();

  for(int idx=t; idx<4096; idx+=256){
    int ll = idx>>7, c = idx&127;
    float xn = (s_x[c][ll]-s_mu[ll])*s_rs[ll]*ln_g[m*128+c] + ln_b[m*128+c];
    s_xn[ll][c] = xn;
    xnb[((size_t)j*LSEQ + l0+ll)*128 + c] = xn;
  }
  __syncthreads();

  const int e = t&127, hh = t>>7;
  for(int ll=hh*16; ll<hh*16+16; ++ll){
    #pragma unroll
    for(int q=0;q<4;q++){
      const float4* xr4 = (const float4*)(&s_xn[ll][q*32]);
      float acc=0.f;
      #pragma unroll
      for(int k4=0;k4<8;k4++){
        float4 xv = xr4[k4];
        acc += xv.x*wreg[k4*4+0] + xv.y*wreg[k4*4+1]
             + xv.z*wreg[k4*4+2] + xv.w*wreg[k4*4+3];
      }
      size_t base = ((size_t)(j*NP+q)*LSEQ + l0+ll)*64;
      if(e<64) xzr[base+e]=acc; else zb[base+e-64]=acc;
    }
  }
}

// ---------- K2: conv + SiLU + x_proj + dt/softplus. 32 l per block, lean LDS, reg windows ----------
__global__ __launch_bounds__(256) void k2_conv_xproj(
  const int* __restrict__ did,
  const float* __restrict__ conv_w, const float* __restrict__ conv_b,
  const float* __restrict__ xp_w, const float* __restrict__ dt_w, const float* __restrict__ dt_b,
  const float* __restrict__ xzr, float* __restrict__ dxb,
  float* __restrict__ bmb, float* __restrict__ cmb)
{
  const int seq = blockIdx.y, j = seq>>2, t = threadIdx.x;
  const int l0 = blockIdx.x*32;
  const int m = mixer_of(did, j);
  const int d = t&63, r = t>>6;          // r = row-group (8 rows each)
  __shared__ float s_xi[32][64];
  __shared__ float s_dbc[32][2];
  __shared__ float s_cwT[4][64];
  __shared__ float s_cb[64], s_dtw[128], s_dtb[64];

  float lz[11];
  #pragma unroll
  for(int i=0;i<11;i++){
    int l = l0 + r*8 - 3 + i;
    lz[i] = (l>=0) ? xzr[((size_t)seq*LSEQ + l)*64 + d] : 0.f;
  }
  { int k=t>>6, dd=t&63; s_cwT[k][dd]=conv_w[m*256+dd*4+k]; }
  if(t<64){ s_cb[t]=conv_b[m*64+t]; s_dtb[t]=dt_b[m*64+t]; }
  if(t<128) s_dtw[t]=dt_w[m*128+t];
  __syncthreads();

  {
    float cw0=s_cwT[0][d], cw1=s_cwT[1][d], cw2=s_cwT[2][d], cw3=s_cwT[3][d], cb=s_cb[d];
    #pragma unroll
    for(int i=0;i<8;i++){
      float xc = cb + lz[i]*cw0 + lz[i+1]*cw1 + lz[i+2]*cw2 + lz[i+3]*cw3;
      s_xi[r*8+i][d] = silu_f(xc);
    }
  }

  float wreg[64];
  if(d<34){
    const float4* wp = (const float4*)(xp_w + (size_t)m*2176 + (size_t)d*64);
    #pragma unroll
    for(int k4=0;k4<16;k4++){
      float4 v = wp[k4];
      wreg[k4*4+0]=v.x; wreg[k4*4+1]=v.y; wreg[k4*4+2]=v.z; wreg[k4*4+3]=v.w;
    }
  }
  __syncthreads();

  if(d<34){
    #pragma unroll
    for(int ip=0; ip<4; ip++){
      int ll = r*8 + ip*2;
      const float4* xa=(const float4*)&s_xi[ll][0];
      const float4* xb=(const float4*)&s_xi[ll+1][0];
      float a0=0.f,a1=0.f,b0=0.f,b1=0.f;
      #pragma unroll
      for(int k=0;k<16;k+=2){
        float4 u=xa[k], u2=xa[k+1], v=xb[k], v2=xb[k+1];
        a0 += u.x *wreg[4*k+0]+u.y *wreg[4*k+1]+u.z *wreg[4*k+2]+u.w *wreg[4*k+3];
        a1 += u2.x*wreg[4*k+4]+u2.y*wreg[4*k+5]+u2.z*wreg[4*k+6]+u2.w*wreg[4*k+7];
        b0 += v.x *wreg[4*k+0]+v.y *wreg[4*k+1]+v.z *wreg[4*k+2]+v.w *wreg[4*k+3];
        b1 += v2.x*wreg[4*k+4]+v2.y*wreg[4*k+5]+v2.z*wreg[4*k+6]+v2.w*wreg[4*k+7];
      }
      float A=a0+a1, Bv=b0+b1;
      if(d<2){ s_dbc[ll][d]=A; s_dbc[ll+1][d]=Bv; }
      else if(d<18){
        bmb[((size_t)seq*LSEQ + l0+ll  )*16 + d-2]=A;
        bmb[((size_t)seq*LSEQ + l0+ll+1)*16 + d-2]=Bv;
      } else {
        cmb[((size_t)seq*LSEQ + l0+ll  )*16 + d-18]=A;
        cmb[((size_t)seq*LSEQ + l0+ll+1)*16 + d-18]=Bv;
      }
    }
  }
  __syncthreads();

  {
    float w0=s_dtw[d*2], w1=s_dtw[d*2+1], bb=s_dtb[d];
    #pragma unroll
    for(int i=0;i<8;i++){
      int ll=r*8+i;
      float dtv = s_dbc[ll][0]*w0 + s_dbc[ll][1]*w1 + bb;
      float dlv = dtv>20.f ? dtv : log1pf(expf(dtv));
      float2 pk; pk.x=dlv; pk.y=s_xi[ll][d];
      *(float2*)(dxb + ((size_t)seq*LSEQ + l0+ll)*128 + d*2) = pk;
    }
  }
}

// ---------------- K3a: per-chunk summaries. 2 chunks/block, 2 waves/chunk (s-split 8 states) ----------------
__global__ __launch_bounds__(256) void k3a_scan_pe(
  const int* __restrict__ did, const float* __restrict__ A_log,
  const float* __restrict__ dxb, const float* __restrict__ bmb,
  float* __restrict__ pb, float* __restrict__ eb)
{
  const int seq=blockIdx.y, j=seq>>2, t=threadIdx.x;
  const int wave=t>>6, d=t&63;
  const int cl=wave>>1, sh=wave&1, sh8=sh*8;
  const int chunk=blockIdx.x*2+cl;
  const int l0=blockIdx.x*2*LC;
  const int m=mixer_of(did,j);
  __shared__ float s_b[2*LC*NS];   // 4KB
  ((float4*)s_b)[t] = ((const float4*)(bmb + ((size_t)seq*LSEQ + l0)*NS))[t];

  float as_h[8], as0;
  {
    const float* ap = A_log + (size_t)m*1024 + d*16;
    as0 = -expf(ap[0])*LOG2E;
    #pragma unroll
    for(int k=0;k<8;k++) as_h[k] = -expf(ap[sh8+k])*LOG2E;
  }
  bool stl = true;
  #pragma unroll
  for(int k=0;k<8;k++){ float ex=(float)(sh8+k+1)*as0; stl = stl && (fabsf(as_h[k]-ex) <= 1e-4f*fabsf(ex)); }
  const bool structured = (__ballot(stl) == ~0ull);

  const float2* dxp=(const float2*)(dxb + ((size_t)seq*LSEQ + (size_t)chunk*LC)*128);
  float E[8];
  #pragma unroll
  for(int k=0;k<8;k++) E[k]=0.f;
  float Sdl=0.f;
  __syncthreads();

  #define ASTEP(i_, dx_, FAST_) { \
    float dl=dx_.x, xv=dx_.y; float u=dl*xv; Sdl+=dl; \
    const float4* bq=(const float4*)(s_b + cl*(LC*NS) + (i_)*NS + sh8); \
    float4 b0=bq[0], b1=bq[1]; \
    float bb[8]={b0.x,b0.y,b0.z,b0.w, b1.x,b1.y,b1.z,b1.w}; \
    float p[8]; \
    if(FAST_){ float q=exp2f(dl*as0); p[0]=exp2f(dl*as_h[0]); \
      _Pragma("unroll") for(int k=1;k<8;k++) p[k]=p[k-1]*q; \
    } else { _Pragma("unroll") for(int k=0;k<8;k++) p[k]=exp2f(dl*as_h[k]); } \
    _Pragma("unroll") for(int k=0;k<8;k++) E[k]=fmaf(p[k],E[k],u*bb[k]); }

  #define ALOOP(FAST_) { \
    float2 dxw[4]; \
    _Pragma("unroll") for(int k=0;k<4;k++) dxw[k]=dxp[k*64+d]; \
    for(int ii=0;ii<LC;ii+=4){ \
      float2 c0=dxw[0],c1=dxw[1],c2=dxw[2],c3=dxw[3]; \
      if(ii+4<LC){ _Pragma("unroll") for(int k=0;k<4;k++) dxw[k]=dxp[(ii+4+k)*64+d]; } \
      ASTEP(ii+0,c0,FAST_); ASTEP(ii+1,c1,FAST_); ASTEP(ii+2,c2,FAST_); ASTEP(ii+3,c3,FAST_); } }

  if(structured){ ALOOP(1) } else { ALOOP(0) }
  #undef ALOOP
  #undef ASTEP

  float P[8];
  #pragma unroll
  for(int k=0;k<8;k++) P[k]=exp2f(Sdl*as_h[k]);
  size_t oo=(((size_t)seq*NC+chunk)*64+d)*16 + sh8;
  float4* pp=(float4*)(pb+oo); float4* ep=(float4*)(eb+oo);
  pp[0]=make_float4(P[0],P[1],P[2],P[3]);
  pp[1]=make_float4(P[4],P[5],P[6],P[7]);
  ep[0]=make_float4(E[0],E[1],E[2],E[3]);
  ep[1]=make_float4(E[4],E[5],E[6],E[7]);
}

// ---------------- K3b: combine chunk summaries, batched prefetch; hs written in-place into p ----------------
__global__ __launch_bounds__(256) void k3b_combine(
  float* p_hs, const float* __restrict__ eb)
{
  const int seq=blockIdx.y, q=blockIdx.x, t=threadIdx.x;
  const size_t elem = (size_t)q*256+t;
  #define OFF(c_) (((size_t)seq*NC+(c_))*1024 + elem)
  float pA[16],eA[16],pB[16],eB[16];
  #pragma unroll
  for(int k=0;k<16;k++){ pA[k]=p_hs[OFF(k)]; eA[k]=eb[OFF(k)]; }
  float h=0.f;
  for(int bt=0; bt<8; bt+=2){
    if(bt+1<8){
      #pragma unroll
      for(int k=0;k<16;k++){ pB[k]=p_hs[OFF((bt+1)*16+k)]; eB[k]=eb[OFF((bt+1)*16+k)]; }
    }
    #pragma unroll
    for(int k=0;k<16;k++){ p_hs[OFF(bt*16+k)]=h; h=fmaf(pA[k],h,eA[k]); }
    if(bt+2<8){
      #pragma unroll
      for(int k=0;k<16;k++){ pA[k]=p_hs[OFF((bt+2)*16+k)]; eA[k]=eb[OFF((bt+2)*16+k)]; }
    }
    #pragma unroll
    for(int k=0;k<16;k++){ p_hs[OFF((bt+1)*16+k)]=h; h=fmaf(pB[k],h,eB[k]); }
  }
  #undef OFF
}

// -------- K3C4: rescan + gate + out_proj + skip. 2 chunks x 2 s-half waves, y planes in LDS --------
__global__ __launch_bounds__(256) void k3c4_scan_outproj(
  const int* __restrict__ did, const float* __restrict__ A_log, const float* __restrict__ Dp,
  const float* __restrict__ dxb,
  const float* __restrict__ bmb, const float* __restrict__ cmb,
  const float* __restrict__ zb, const float* __restrict__ hsb,
  const float* __restrict__ out_w, const float* __restrict__ skipv,
  const float* __restrict__ xnb, float* __restrict__ xmb)
{
  const int seq=blockIdx.y, j=seq>>2, p=seq&3, t=threadIdx.x;
  const int wave=t>>6, d=t&63;
  const int cl=wave>>1, sh=wave&1, sh8=sh*8;
  const int chunk=blockIdx.x*2+cl;
  const int l0=blockIdx.x*2*LC;            // 64 l per block
  const int m=mixer_of(did,j);
  __shared__ float s_b[2*LC*NS];           // 4KB
  __shared__ float s_c[2*LC*NS];           // 4KB
  __shared__ float s_y0[64*64];            // 16KB  (states 0-7 partial y, then gated y)
  __shared__ float s_y1[64*64];            // 16KB  (states 8-15 partial y)
  {
    const float4* bsrc=(const float4*)(bmb + ((size_t)seq*LSEQ + l0)*NS);
    const float4* csrc=(const float4*)(cmb + ((size_t)seq*LSEQ + l0)*NS);
    ((float4*)s_b)[t]=bsrc[t];
    ((float4*)s_c)[t]=csrc[t];
  }
  float as_h[8], as0;
  {
    const float* ap = A_log + (size_t)m*1024 + d*16;
    as0 = -expf(ap[0])*LOG2E;
    #pragma unroll
    for(int k=0;k<8;k++) as_h[k] = -expf(ap[sh8+k])*LOG2E;
  }
  bool stl = true;
  #pragma unroll
  for(int k=0;k<8;k++){ float ex=(float)(sh8+k+1)*as0; stl = stl && (fabsf(as_h[k]-ex) <= 1e-4f*fabsf(ex)); }
  const bool structured = (__ballot(stl) == ~0ull);

  const float dpv2 = (sh==0) ? Dp[m*64+d] : 0.f;
  float h[8];
  {
    const float4* hp=(const float4*)(hsb + (((size_t)seq*NC+chunk)*64+d)*16 + sh8);
    float4 v0=hp[0], v1=hp[1];
    h[0]=v0.x; h[1]=v0.y; h[2]=v0.z; h[3]=v0.w;
    h[4]=v1.x; h[5]=v1.y; h[6]=v1.z; h[7]=v1.w;
  }
  const float2* dxp=(const float2*)(dxb + ((size_t)seq*LSEQ + (size_t)chunk*LC)*128);
  float* s_yw = sh ? s_y1 : s_y0;
  __syncthreads();

  #define CSTEP(i_, dx_, FAST_) { \
    float dl=dx_.x, xv=dx_.y; float u=dl*xv; \
    const float4* bq=(const float4*)(s_b + cl*(LC*NS) + (i_)*NS + sh8); \
    const float4* cq=(const float4*)(s_c + cl*(LC*NS) + (i_)*NS + sh8); \
    float4 b0=bq[0],b1=bq[1],c0=cq[0],c1=cq[1]; \
    float bb[8]={b0.x,b0.y,b0.z,b0.w, b1.x,b1.y,b1.z,b1.w}; \
    float cc[8]={c0.x,c0.y,c0.z,c0.w, c1.x,c1.y,c1.z,c1.w}; \
    float pz[8]; \
    if(FAST_){ float q=exp2f(dl*as0); pz[0]=exp2f(dl*as_h[0]); \
      _Pragma("unroll") for(int k=1;k<8;k++) pz[k]=pz[k-1]*q; \
    } else { _Pragma("unroll") for(int k=0;k<8;k++) pz[k]=exp2f(dl*as_h[k]); } \
    float ya=0.f, yb2=0.f; \
    _Pragma("unroll") for(int k=0;k<8;k++){ \
      h[k]=fmaf(pz[k],h[k],u*bb[k]); \
      float hv=h[k]*cc[k]; \
      if(k&1) yb2+=hv; else ya+=hv; } \
    float y=ya+yb2; y=fmaf(dpv2,xv,y); \
    s_yw[(cl*LC+(i_))*64 + d]=y; }

  #define CLOOP(FAST_) { \
    float2 dxw[4]; \
    _Pragma("unroll") for(int k=0;k<4;k++) dxw[k]=dxp[k*64+d]; \
    for(int ii=0;ii<LC;ii+=4){ \
      float2 c0w=dxw[0],c1w=dxw[1],c2w=dxw[2],c3w=dxw[3]; \
      if(ii+4<LC){ _Pragma("unroll") for(int k=0;k<4;k++) dxw[k]=dxp[(ii+4+k)*64+d]; } \
      CSTEP(ii+0,c0w,FAST_); CSTEP(ii+1,c1w,FAST_); CSTEP(ii+2,c2w,FAST_); CSTEP(ii+3,c3w,FAST_); } }

  if(structured){ CLOOP(1) } else { CLOOP(0) }
  #undef CLOOP
  #undef CSTEP

  __syncthreads();
  // gate pass: yg = (y0+y1)*silu(z), into s_y0
  {
    const float* zp = zb + ((size_t)seq*LSEQ + l0)*64;
    #pragma unroll
    for(int it=0; it<16; ++it){
      int idx = t + it*256;
      float ysum = s_y0[idx] + s_y1[idx];
      s_y0[idx] = ysum * silu_f(zp[idx]);
    }
  }
  // out_proj weights (loaded while gate pass results drain)
  const int o=t&31, grp=t>>5;
  float wreg[64];
  {
    const float4* wp=(const float4*)(out_w + (size_t)m*2048 + (size_t)o*64);
    #pragma unroll
    for(int k4=0;k4<16;k4++){
      float4 v=wp[k4];
      wreg[k4*4+0]=v.x; wreg[k4*4+1]=v.y; wreg[k4*4+2]=v.z; wreg[k4*4+3]=v.w;
    }
  }
  const float sk=skipv[m];
  __syncthreads();
  // epilogue: out_proj(32x64) + skip over this block's 64 l
  for(int ll=grp; ll<64; ll+=8){
    const float4* ya=(const float4*)&s_y0[ll*64];
    float a0=0.f,a1=0.f;
    #pragma unroll
    for(int k=0;k<16;k+=2){
      float4 u=ya[k], u2=ya[k+1];
      a0 += u.x *wreg[4*k+0]+u.y *wreg[4*k+1]+u.z *wreg[4*k+2]+u.w *wreg[4*k+3];
      a1 += u2.x*wreg[4*k+4]+u2.y*wreg[4*k+5]+u2.z*wreg[4*k+6]+u2.w*wreg[4*k+7];
    }
    size_t xidx=((size_t)j*LSEQ + l0+ll)*128 + p*32 + o;
    xmb[xidx]=(a0+a1) + sk*xnb[xidx];
  }
}

// ---------------- K5: LN2 + proj, both experts, 16 l per block ----------------
__global__ __launch_bounds__(256) void k5_ln2_proj(
  const int* __restrict__ did, const float* __restrict__ ln_g, const float* __restrict__ ln_b,
  const float* __restrict__ proj_w, const float* __restrict__ proj_b,
  const float* __restrict__ xmb, float* __restrict__ out)
{
  const int b=blockIdx.y, l0=blockIdx.x*16, t=threadIdx.x;
  const int eh = t>>7, local = t&127;
  const int j = 2*b+eh;
  const int m = mixer_of(did, j);
  __shared__ float s_xn[2][16][132];
  __shared__ float s_comb[16][132];
  __shared__ float s_murs[2][16][2];

  for(int idx=local; idx<2048; idx+=128){
    int ll=idx>>7, c=idx&127;
    s_xn[eh][ll][c] = xmb[((size_t)j*LSEQ + l0+ll)*128 + c];
  }
  __syncthreads();
  {
    const int lane = t&63;
    const int g = lane&7, lw = lane>>3;
    const int ll = ((t>>6)&1)*8 + lw;
    float sum=0.f;
    #pragma unroll
    for(int k=0;k<16;k++) sum += s_xn[eh][ll][g*16+k];
    sum += __shfl_xor(sum,1); sum += __shfl_xor(sum,2); sum += __shfl_xor(sum,4);
    float mu = sum*(1.f/128.f);
    float vs=0.f;
    #pragma unroll
    for(int k=0;k<16;k++){ float dv=s_xn[eh][ll][g*16+k]-mu; vs+=dv*dv; }
    vs += __shfl_xor(vs,1); vs += __shfl_xor(vs,2); vs += __shfl_xor(vs,4);
    if(g==0){ s_murs[eh][ll][0]=mu; s_murs[eh][ll][1]=rsqrtf(vs*(1.f/128.f)+1e-5f); }
  }
  __syncthreads();
  for(int idx=local; idx<2048; idx+=128){
    int ll=idx>>7, c=idx&127;
    float xn=(s_xn[eh][ll][c]-s_murs[eh][ll][0])*s_murs[eh][ll][1]*ln_g[m*128+c]+ln_b[m*128+c];
    s_xn[eh][ll][c]=xn;
  }
  __syncthreads();
  float acc[16];
  #pragma unroll
  for(int ll=0;ll<16;ll++) acc[ll]=0.f;
  {
    const float4* pw4 = (const float4*)(proj_w + (size_t)m*16384 + (size_t)local*128);
    #pragma unroll 4
    for(int c4=0;c4<32;c4++){
      float4 w = pw4[c4];
      int c = c4*4;
      #pragma unroll
      for(int ll=0;ll<16;ll++){
        acc[ll] += w.x*s_xn[eh][ll][c] + w.y*s_xn[eh][ll][c+1]
                 + w.z*s_xn[eh][ll][c+2] + w.w*s_xn[eh][ll][c+3];
      }
    }
  }
  float pb_v = proj_b[m*128+local];
  if(eh==0){
    #pragma unroll
    for(int ll=0;ll<16;ll++) s_comb[ll][local]=acc[ll]+pb_v;
  }
  __syncthreads();
  if(eh==1){
    #pragma unroll
    for(int ll=0;ll<16;ll++) s_comb[ll][local]+=acc[ll]+pb_v;
  }
  __syncthreads();
  for(int idx=t; idx<2048; idx+=256){
    int o=idx>>4, ll=idx&15;
    out[((size_t)b*128+o)*LSEQ + l0+ll] = s_comb[ll][o];
  }
}

extern "C" void kernel_launch(void* const* d_in, const int* in_sizes, int n_in,
                              void* d_out, int out_size, void* d_ws, size_t ws_size,
                              hipStream_t stream) {
  const float* x      = (const float*)d_in[0];
  const int*   did    = (const int*)d_in[1];
  const float* ln_g   = (const float*)d_in[2];
  const float* ln_b   = (const float*)d_in[3];
  const float* in_w   = (const float*)d_in[4];
  const float* conv_w = (const float*)d_in[5];
  const float* conv_b = (const float*)d_in[6];
  const float* xp_w   = (const float*)d_in[7];
  const float* dt_w   = (const float*)d_in[8];
  const float* dt_b   = (const float*)d_in[9];
  const float* A_log  = (const float*)d_in[10];
  const float* Dp     = (const float*)d_in[11];
  const float* out_w  = (const float*)d_in[12];
  const float* proj_w = (const float*)d_in[13];
  const float* proj_b = (const float*)d_in[14];
  const float* skipv  = (const float*)d_in[15];
  float* out = (float*)d_out;
  float* ws  = (float*)d_ws;

  float* xnb = ws;                                   // NJ*L*128   (2.10M f)
  float* xzr = xnb + (size_t)NJ*LSEQ*128;            // NSEQ*L*64  (4.19M f) dead after k2 -> pb,eb
  float* zb  = xzr + (size_t)NSEQ*LSEQ*64;           // NSEQ*L*64  z (read-only after k1)
  float* dxb = zb  + (size_t)NSEQ*LSEQ*64;           // NSEQ*L*64*2 packed (dl,xi)
  float* bmb = dxb + (size_t)NSEQ*LSEQ*128;          // NSEQ*L*16
  float* cmb = bmb + (size_t)NSEQ*LSEQ*16;           // NSEQ*L*16
  float* xmb = cmb + (size_t)NSEQ*LSEQ*16;           // NJ*L*128
  float* pb  = xzr;                                  // NSEQ*NC*1024 = 2.10M; hs in-place
  float* eb  = xzr + (size_t)NSEQ*NC*1024;           // 2.10M (fits in xzr's 4.19M)
  float* hsb = pb;

  hipLaunchKernelGGL(k1_ln_inproj, dim3(LSEQ/32,NJ), dim3(256), 0, stream,
                     x,did,ln_g,ln_b,in_w,xnb,xzr,zb);
  hipLaunchKernelGGL(k2_conv_xproj, dim3(LSEQ/32,NSEQ), dim3(256), 0, stream,
                     did,conv_w,conv_b,xp_w,dt_w,dt_b,xzr,dxb,bmb,cmb);
  hipLaunchKernelGGL(k3a_scan_pe, dim3(NC/2,NSEQ), dim3(256), 0, stream,
                     did,A_log,dxb,bmb,pb,eb);
  hipLaunchKernelGGL(k3b_combine, dim3(4,NSEQ), dim3(256), 0, stream, pb,eb);
  hipLaunchKernelGGL(k3c4_scan_outproj, dim3(NC/2,NSEQ), dim3(256), 0, stream,
                     did,A_log,Dp,dxb,bmb,cmb,zb,hsb,out_w,skipv,xnb,xmb);
  hipLaunchKernelGGL(k5_ln2_proj, dim3(LSEQ/16,2), dim3(256), 0, stream,
                     did,ln_g,ln_b,proj_w,proj_b,xmb,out);
}

// Round 8
// 132.217 us; speedup vs baseline: 1.7229x; 1.0511x over previous
//
#include <hip/hip_runtime.h>
#include <math.h>

#define LSEQ 4096   // D*H*W = 16*16*16
#define CIN  128
#define DI   64     // d_inner
#define NS   16     // d_state
#define NP   4      // parts
#define NJ   4      // jobs = (b, mixer) pairs
#define NSEQ 16     // NJ * NP independent mamba sequences
#define NC   128    // scan chunks
#define LC   32     // chunk length (NC*LC = LSEQ)
#define LOG2E 1.44269504f

__device__ __forceinline__ int mixer_of(const int* did, int j){
  if((j&1)==0) return 0;
  int d = did[j>>1];
  return 1 + (d < 1 ? d : 1);
}
__device__ __forceinline__ float silu_f(float x){ return x/(1.f+expf(-x)); }

// ---------------- K1: LN1 + in_proj. 32 l per block, w rows in registers ----------------
__global__ __launch_bounds__(256) void k1_ln_inproj(
  const float* __restrict__ x, const int* __restrict__ did,
  const float* __restrict__ ln_g, const float* __restrict__ ln_b,
  const float* __restrict__ in_w,
  float* __restrict__ xnb, float* __restrict__ xzr, float* __restrict__ zb)
{
  const int j = blockIdx.y, b = j>>1, t = threadIdx.x;
  const int l0 = blockIdx.x*32;
  const int m = mixer_of(did, j);
  __shared__ float s_x[128][33];    // [c][ll]
  __shared__ float s_xn[32][132];   // [ll][c]  (132 = 4*33: rows 16B aligned)
  __shared__ float s_mu[32], s_rs[32];

  for(int idx=t; idx<4096; idx+=256){
    int c = idx>>5, ll = idx&31;
    s_x[c][ll] = x[((size_t)b*CIN+c)*LSEQ + l0+ll];
  }
  float wreg[32];
  {
    const float4* wp = (const float4*)(in_w + (size_t)m*4096 + (size_t)(t&127)*32);
    #pragma unroll
    for(int i=0;i<8;i++){
      float4 v = wp[i];
      wreg[i*4+0]=v.x; wreg[i*4+1]=v.y; wreg[i*4+2]=v.z; wreg[i*4+3]=v.w;
    }
  }
  __syncthreads();

  {
    const int wv = t>>6, lane = t&63;
    const int g = lane&7, lw = lane>>3;
    const int ll = wv*8+lw;
    float sum=0.f;
    #pragma unroll
    for(int k=0;k<16;k++) sum += s_x[g*16+k][ll];
    sum += __shfl_xor(sum,1); sum += __shfl_xor(sum,2); sum += __shfl_xor(sum,4);
    float mu = sum*(1.f/128.f);
    float vs=0.f;
    #pragma unroll
    for(int k=0;k<16;k++){ float dv = s_x[g*16+k][ll]-mu; vs += dv*dv; }
    vs += __shfl_xor(vs,1); vs += __shfl_xor(vs,2); vs += __shfl_xor(vs,4);
    if(g==0){ s_mu[ll]=mu; s_rs[ll]=rsqrtf(vs*(1.f/128.f)+1e-5f); }
  }
  __syncthreads();

  for(int idx=t; idx<4096; idx+=256){
    int ll = idx>>7, c = idx&127;
    float xn = (s_x[c][ll]-s_mu[ll])*s_rs[ll]*ln_g[m*128+c] + ln_b[m*128+c];
    s_xn[ll][c] = xn;
    xnb[((size_t)j*LSEQ + l0+ll)*128 + c] = xn;
  }
  __syncthreads();

  const int e = t&127, hh = t>>7;
  for(int ll=hh*16; ll<hh*16+16; ++ll){
    #pragma unroll
    for(int q=0;q<4;q++){
      const float4* xr4 = (const float4*)(&s_xn[ll][q*32]);
      float acc=0.f;
      #pragma unroll
      for(int k4=0;k4<8;k4++){
        float4 xv = xr4[k4];
        acc += xv.x*wreg[k4*4+0] + xv.y*wreg[k4*4+1]
             + xv.z*wreg[k4*4+2] + xv.w*wreg[k4*4+3];
      }
      size_t base = ((size_t)(j*NP+q)*LSEQ + l0+ll)*64;
      if(e<64) xzr[base+e]=acc; else zb[base+e-64]=acc;
    }
  }
}

// ---- K2: conv + SiLU + x_proj + dt/softplus + FUSED chunk summary (P,E). 32 l = 1 chunk per block ----
__global__ __launch_bounds__(256) void k2_conv_xproj_pe(
  const int* __restrict__ did,
  const float* __restrict__ conv_w, const float* __restrict__ conv_b,
  const float* __restrict__ xp_w, const float* __restrict__ dt_w, const float* __restrict__ dt_b,
  const float* __restrict__ A_log,
  const float* __restrict__ xzr, float* __restrict__ dxb,
  float* __restrict__ bmb, float* __restrict__ cmb,
  float* __restrict__ pb, float* __restrict__ eb)
{
  const int seq = blockIdx.y, j = seq>>2, t = threadIdx.x;
  const int chunk = blockIdx.x;
  const int l0 = chunk*32;
  const int m = mixer_of(did, j);
  const int d = t&63, r = t>>6;          // r = row-group (8 rows each)
  __shared__ float s_xi[32][64];
  __shared__ float s_dl[32][64];
  __shared__ float s_bS[32][16];
  __shared__ float s_dbc[32][2];
  __shared__ float s_cwT[4][64];
  __shared__ float s_cb[64], s_dtw[128], s_dtb[64];

  float lz[11];
  #pragma unroll
  for(int i=0;i<11;i++){
    int l = l0 + r*8 - 3 + i;
    lz[i] = (l>=0) ? xzr[((size_t)seq*LSEQ + l)*64 + d] : 0.f;
  }
  { int k=t>>6, dd=t&63; s_cwT[k][dd]=conv_w[m*256+dd*4+k]; }
  if(t<64){ s_cb[t]=conv_b[m*64+t]; s_dtb[t]=dt_b[m*64+t]; }
  if(t<128) s_dtw[t]=dt_w[m*128+t];
  __syncthreads();

  {
    float cw0=s_cwT[0][d], cw1=s_cwT[1][d], cw2=s_cwT[2][d], cw3=s_cwT[3][d], cb=s_cb[d];
    #pragma unroll
    for(int i=0;i<8;i++){
      float xc = cb + lz[i]*cw0 + lz[i+1]*cw1 + lz[i+2]*cw2 + lz[i+3]*cw3;
      s_xi[r*8+i][d] = silu_f(xc);
    }
  }

  float wreg[64];
  if(d<34){
    const float4* wp = (const float4*)(xp_w + (size_t)m*2176 + (size_t)d*64);
    #pragma unroll
    for(int k4=0;k4<16;k4++){
      float4 v = wp[k4];
      wreg[k4*4+0]=v.x; wreg[k4*4+1]=v.y; wreg[k4*4+2]=v.z; wreg[k4*4+3]=v.w;
    }
  }
  __syncthreads();

  if(d<34){
    #pragma unroll
    for(int ip=0; ip<4; ip++){
      int ll = r*8 + ip*2;
      const float4* xa=(const float4*)&s_xi[ll][0];
      const float4* xb=(const float4*)&s_xi[ll+1][0];
      float a0=0.f,a1=0.f,b0=0.f,b1=0.f;
      #pragma unroll
      for(int k=0;k<16;k+=2){
        float4 u=xa[k], u2=xa[k+1], v=xb[k], v2=xb[k+1];
        a0 += u.x *wreg[4*k+0]+u.y *wreg[4*k+1]+u.z *wreg[4*k+2]+u.w *wreg[4*k+3];
        a1 += u2.x*wreg[4*k+4]+u2.y*wreg[4*k+5]+u2.z*wreg[4*k+6]+u2.w*wreg[4*k+7];
        b0 += v.x *wreg[4*k+0]+v.y *wreg[4*k+1]+v.z *wreg[4*k+2]+v.w *wreg[4*k+3];
        b1 += v2.x*wreg[4*k+4]+v2.y*wreg[4*k+5]+v2.z*wreg[4*k+6]+v2.w*wreg[4*k+7];
      }
      float A=a0+a1, Bv=b0+b1;
      if(d<2){ s_dbc[ll][d]=A; s_dbc[ll+1][d]=Bv; }
      else if(d<18){
        s_bS[ll][d-2]=A; s_bS[ll+1][d-2]=Bv;
        bmb[((size_t)seq*LSEQ + l0+ll  )*16 + d-2]=A;
        bmb[((size_t)seq*LSEQ + l0+ll+1)*16 + d-2]=Bv;
      } else {
        cmb[((size_t)seq*LSEQ + l0+ll  )*16 + d-18]=A;
        cmb[((size_t)seq*LSEQ + l0+ll+1)*16 + d-18]=Bv;
      }
    }
  }
  __syncthreads();

  {
    float w0=s_dtw[d*2], w1=s_dtw[d*2+1], bb=s_dtb[d];
    #pragma unroll
    for(int i=0;i<8;i++){
      int ll=r*8+i;
      float dtv = s_dbc[ll][0]*w0 + s_dbc[ll][1]*w1 + bb;
      float dlv = dtv>20.f ? dtv : log1pf(expf(dtv));
      s_dl[ll][d]=dlv;
      float2 pk; pk.x=dlv; pk.y=s_xi[ll][d];
      *(float2*)(dxb + ((size_t)seq*LSEQ + l0+ll)*128 + d*2) = pk;
    }
  }
  __syncthreads();

  // ---- fused chunk summary: thread = (d, s-quad sq=r), 4 states each ----
  {
    const int sq = r;              // wave-uniform (r = t>>6)
    float as_q[4], as0;
    {
      const float* ap = A_log + (size_t)m*1024 + d*16;
      as0 = -expf(ap[0])*LOG2E;
      #pragma unroll
      for(int k=0;k<4;k++) as_q[k] = -expf(ap[sq*4+k])*LOG2E;
    }
    bool stl = true;
    #pragma unroll
    for(int k=0;k<4;k++){ float ex=(float)(sq*4+k+1)*as0; stl = stl && (fabsf(as_q[k]-ex) <= 1e-4f*fabsf(ex)); }
    const bool structured = (__ballot(stl) == ~0ull);

    float E[4] = {0.f,0.f,0.f,0.f};
    float Sdl = 0.f;

    #define PSTEP(i_, FAST_) { \
      float dl = s_dl[i_][d]; \
      float u  = dl * s_xi[i_][d]; \
      Sdl += dl; \
      const float4 bv = *(const float4*)(&s_bS[i_][sq*4]); \
      float bb[4]={bv.x,bv.y,bv.z,bv.w}; \
      float p[4]; \
      if(FAST_){ float q=exp2f(dl*as0); p[0]=exp2f(dl*as_q[0]); \
        p[1]=p[0]*q; p[2]=p[1]*q; p[3]=p[2]*q; \
      } else { _Pragma("unroll") for(int k=0;k<4;k++) p[k]=exp2f(dl*as_q[k]); } \
      _Pragma("unroll") for(int k=0;k<4;k++) E[k]=fmaf(p[k],E[k],u*bb[k]); }

    if(structured){
      #pragma unroll 4
      for(int i=0;i<LC;i++){ PSTEP(i,1) }
    } else {
      #pragma unroll 4
      for(int i=0;i<LC;i++){ PSTEP(i,0) }
    }
    #undef PSTEP

    size_t oo=(((size_t)seq*NC+chunk)*64+d)*16 + sq*4;
    *(float4*)(pb+oo) = make_float4(exp2f(Sdl*as_q[0]),exp2f(Sdl*as_q[1]),
                                    exp2f(Sdl*as_q[2]),exp2f(Sdl*as_q[3]));
    *(float4*)(eb+oo) = make_float4(E[0],E[1],E[2],E[3]);
  }
}

// ---------------- K3b: combine chunk summaries, batched prefetch; hs written in-place into p ----------------
__global__ __launch_bounds__(256) void k3b_combine(
  float* p_hs, const float* __restrict__ eb)
{
  const int seq=blockIdx.y, q=blockIdx.x, t=threadIdx.x;
  const size_t elem = (size_t)q*256+t;
  #define OFF(c_) (((size_t)seq*NC+(c_))*1024 + elem)
  float pA[16],eA[16],pB[16],eB[16];
  #pragma unroll
  for(int k=0;k<16;k++){ pA[k]=p_hs[OFF(k)]; eA[k]=eb[OFF(k)]; }
  float h=0.f;
  for(int bt=0; bt<8; bt+=2){
    if(bt+1<8){
      #pragma unroll
      for(int k=0;k<16;k++){ pB[k]=p_hs[OFF((bt+1)*16+k)]; eB[k]=eb[OFF((bt+1)*16+k)]; }
    }
    #pragma unroll
    for(int k=0;k<16;k++){ p_hs[OFF(bt*16+k)]=h; h=fmaf(pA[k],h,eA[k]); }
    if(bt+2<8){
      #pragma unroll
      for(int k=0;k<16;k++){ pA[k]=p_hs[OFF((bt+2)*16+k)]; eA[k]=eb[OFF((bt+2)*16+k)]; }
    }
    #pragma unroll
    for(int k=0;k<16;k++){ p_hs[OFF((bt+1)*16+k)]=h; h=fmaf(pB[k],h,eB[k]); }
  }
  #undef OFF
}

// -------- K3C4: rescan + gate + out_proj + skip. 2 chunks x 2 s-half waves, y planes in LDS --------
__global__ __launch_bounds__(256) void k3c4_scan_outproj(
  const int* __restrict__ did, const float* __restrict__ A_log, const float* __restrict__ Dp,
  const float* __restrict__ dxb,
  const float* __restrict__ bmb, const float* __restrict__ cmb,
  const float* __restrict__ zb, const float* __restrict__ hsb,
  const float* __restrict__ out_w, const float* __restrict__ skipv,
  const float* __restrict__ xnb, float* __restrict__ xmb)
{
  const int seq=blockIdx.y, j=seq>>2, p=seq&3, t=threadIdx.x;
  const int wave=t>>6, d=t&63;
  const int cl=wave>>1, sh=wave&1, sh8=sh*8;
  const int chunk=blockIdx.x*2+cl;
  const int l0=blockIdx.x*2*LC;            // 64 l per block
  const int m=mixer_of(did,j);
  __shared__ float s_b[2*LC*NS];           // 4KB
  __shared__ float s_c[2*LC*NS];           // 4KB
  __shared__ float s_y0[64*64];            // 16KB  (states 0-7 partial y, then gated y)
  __shared__ float s_y1[64*64];            // 16KB  (states 8-15 partial y)
  {
    const float4* bsrc=(const float4*)(bmb + ((size_t)seq*LSEQ + l0)*NS);
    const float4* csrc=(const float4*)(cmb + ((size_t)seq*LSEQ + l0)*NS);
    ((float4*)s_b)[t]=bsrc[t];
    ((float4*)s_c)[t]=csrc[t];
  }
  float as_h[8], as0;
  {
    const float* ap = A_log + (size_t)m*1024 + d*16;
    as0 = -expf(ap[0])*LOG2E;
    #pragma unroll
    for(int k=0;k<8;k++) as_h[k] = -expf(ap[sh8+k])*LOG2E;
  }
  bool stl = true;
  #pragma unroll
  for(int k=0;k<8;k++){ float ex=(float)(sh8+k+1)*as0; stl = stl && (fabsf(as_h[k]-ex) <= 1e-4f*fabsf(ex)); }
  const bool structured = (__ballot(stl) == ~0ull);

  const float dpv2 = (sh==0) ? Dp[m*64+d] : 0.f;
  float h[8];
  {
    const float4* hp=(const float4*)(hsb + (((size_t)seq*NC+chunk)*64+d)*16 + sh8);
    float4 v0=hp[0], v1=hp[1];
    h[0]=v0.x; h[1]=v0.y; h[2]=v0.z; h[3]=v0.w;
    h[4]=v1.x; h[5]=v1.y; h[6]=v1.z; h[7]=v1.w;
  }
  const float2* dxp=(const float2*)(dxb + ((size_t)seq*LSEQ + (size_t)chunk*LC)*128);
  float* s_yw = sh ? s_y1 : s_y0;
  __syncthreads();

  #define CSTEP(i_, dx_, FAST_) { \
    float dl=dx_.x, xv=dx_.y; float u=dl*xv; \
    const float4* bq=(const float4*)(s_b + cl*(LC*NS) + (i_)*NS + sh8); \
    const float4* cq=(const float4*)(s_c + cl*(LC*NS) + (i_)*NS + sh8); \
    float4 b0=bq[0],b1=bq[1],c0=cq[0],c1=cq[1]; \
    float bb[8]={b0.x,b0.y,b0.z,b0.w, b1.x,b1.y,b1.z,b1.w}; \
    float cc[8]={c0.x,c0.y,c0.z,c0.w, c1.x,c1.y,c1.z,c1.w}; \
    float pz[8]; \
    if(FAST_){ float q=exp2f(dl*as0); pz[0]=exp2f(dl*as_h[0]); \
      _Pragma("unroll") for(int k=1;k<8;k++) pz[k]=pz[k-1]*q; \
    } else { _Pragma("unroll") for(int k=0;k<8;k++) pz[k]=exp2f(dl*as_h[k]); } \
    float ya=0.f, yb2=0.f; \
    _Pragma("unroll") for(int k=0;k<8;k++){ \
      h[k]=fmaf(pz[k],h[k],u*bb[k]); \
      float hv=h[k]*cc[k]; \
      if(k&1) yb2+=hv; else ya+=hv; } \
    float y=ya+yb2; y=fmaf(dpv2,xv,y); \
    s_yw[(cl*LC+(i_))*64 + d]=y; }

  #define CLOOP(FAST_) { \
    float2 dxw[4]; \
    _Pragma("unroll") for(int k=0;k<4;k++) dxw[k]=dxp[k*64+d]; \
    for(int ii=0;ii<LC;ii+=4){ \
      float2 c0w=dxw[0],c1w=dxw[1],c2w=dxw[2],c3w=dxw[3]; \
      if(ii+4<LC){ _Pragma("unroll") for(int k=0;k<4;k++) dxw[k]=dxp[(ii+4+k)*64+d]; } \
      CSTEP(ii+0,c0w,FAST_); CSTEP(ii+1,c1w,FAST_); CSTEP(ii+2,c2w,FAST_); CSTEP(ii+3,c3w,FAST_); } }

  if(structured){ CLOOP(1) } else { CLOOP(0) }
  #undef CLOOP
  #undef CSTEP

  __syncthreads();
  // gate pass: yg = (y0+y1)*silu(z), into s_y0
  {
    const float* zp = zb + ((size_t)seq*LSEQ + l0)*64;
    #pragma unroll
    for(int it=0; it<16; ++it){
      int idx = t + it*256;
      float ysum = s_y0[idx] + s_y1[idx];
      s_y0[idx] = ysum * silu_f(zp[idx]);
    }
  }
  // out_proj weights (loaded while gate pass results drain)
  const int o=t&31, grp=t>>5;
  float wreg[64];
  {
    const float4* wp=(const float4*)(out_w + (size_t)m*2048 + (size_t)o*64);
    #pragma unroll
    for(int k4=0;k4<16;k4++){
      float4 v=wp[k4];
      wreg[k4*4+0]=v.x; wreg[k4*4+1]=v.y; wreg[k4*4+2]=v.z; wreg[k4*4+3]=v.w;
    }
  }
  const float sk=skipv[m];
  __syncthreads();
  // epilogue: out_proj(32x64) + skip over this block's 64 l
  for(int ll=grp; ll<64; ll+=8){
    const float4* ya=(const float4*)&s_y0[ll*64];
    float a0=0.f,a1=0.f;
    #pragma unroll
    for(int k=0;k<16;k+=2){
      float4 u=ya[k], u2=ya[k+1];
      a0 += u.x *wreg[4*k+0]+u.y *wreg[4*k+1]+u.z *wreg[4*k+2]+u.w *wreg[4*k+3];
      a1 += u2.x*wreg[4*k+4]+u2.y*wreg[4*k+5]+u2.z*wreg[4*k+6]+u2.w*wreg[4*k+7];
    }
    size_t xidx=((size_t)j*LSEQ + l0+ll)*128 + p*32 + o;
    xmb[xidx]=(a0+a1) + sk*xnb[xidx];
  }
}

// ---------------- K5: LN2 + proj, both experts, 16 l per block ----------------
__global__ __launch_bounds__(256) void k5_ln2_proj(
  const int* __restrict__ did, const float* __restrict__ ln_g, const float* __restrict__ ln_b,
  const float* __restrict__ proj_w, const float* __restrict__ proj_b,
  const float* __restrict__ xmb, float* __restrict__ out)
{
  const int b=blockIdx.y, l0=blockIdx.x*16, t=threadIdx.x;
  const int eh = t>>7, local = t&127;
  const int j = 2*b+eh;
  const int m = mixer_of(did, j);
  __shared__ float s_xn[2][16][132];
  __shared__ float s_comb[16][132];
  __shared__ float s_murs[2][16][2];

  for(int idx=local; idx<2048; idx+=128){
    int ll=idx>>7, c=idx&127;
    s_xn[eh][ll][c] = xmb[((size_t)j*LSEQ + l0+ll)*128 + c];
  }
  __syncthreads();
  {
    const int lane = t&63;
    const int g = lane&7, lw = lane>>3;
    const int ll = ((t>>6)&1)*8 + lw;
    float sum=0.f;
    #pragma unroll
    for(int k=0;k<16;k++) sum += s_xn[eh][ll][g*16+k];
    sum += __shfl_xor(sum,1); sum += __shfl_xor(sum,2); sum += __shfl_xor(sum,4);
    float mu = sum*(1.f/128.f);
    float vs=0.f;
    #pragma unroll
    for(int k=0;k<16;k++){ float dv=s_xn[eh][ll][g*16+k]-mu; vs+=dv*dv; }
    vs += __shfl_xor(vs,1); vs += __shfl_xor(vs,2); vs += __shfl_xor(vs,4);
    if(g==0){ s_murs[eh][ll][0]=mu; s_murs[eh][ll][1]=rsqrtf(vs*(1.f/128.f)+1e-5f); }
  }
  __syncthreads();
  for(int idx=local; idx<2048; idx+=128){
    int ll=idx>>7, c=idx&127;
    float xn=(s_xn[eh][ll][c]-s_murs[eh][ll][0])*s_murs[eh][ll][1]*ln_g[m*128+c]+ln_b[m*128+c];
    s_xn[eh][ll][c]=xn;
  }
  __syncthreads();
  float acc[16];
  #pragma unroll
  for(int ll=0;ll<16;ll++) acc[ll]=0.f;
  {
    const float4* pw4 = (const float4*)(proj_w + (size_t)m*16384 + (size_t)local*128);
    #pragma unroll 4
    for(int c4=0;c4<32;c4++){
      float4 w = pw4[c4];
      int c = c4*4;
      #pragma unroll
      for(int ll=0;ll<16;ll++){
        acc[ll] += w.x*s_xn[eh][ll][c] + w.y*s_xn[eh][ll][c+1]
                 + w.z*s_xn[eh][ll][c+2] + w.w*s_xn[eh][ll][c+3];
      }
    }
  }
  float pb_v = proj_b[m*128+local];
  if(eh==0){
    #pragma unroll
    for(int ll=0;ll<16;ll++) s_comb[ll][local]=acc[ll]+pb_v;
  }
  __syncthreads();
  if(eh==1){
    #pragma unroll
    for(int ll=0;ll<16;ll++) s_comb[ll][local]+=acc[ll]+pb_v;
  }
  __syncthreads();
  for(int idx=t; idx<2048; idx+=256){
    int o=idx>>4, ll=idx&15;
    out[((size_t)b*128+o)*LSEQ + l0+ll] = s_comb[ll][o];
  }
}

extern "C" void kernel_launch(void* const* d_in, const int* in_sizes, int n_in,
                              void* d_out, int out_size, void* d_ws, size_t ws_size,
                              hipStream_t stream) {
  const float* x      = (const float*)d_in[0];
  const int*   did    = (const int*)d_in[1];
  const float* ln_g   = (const float*)d_in[2];
  const float* ln_b   = (const float*)d_in[3];
  const float* in_w   = (const float*)d_in[4];
  const float* conv_w = (const float*)d_in[5];
  const float* conv_b = (const float*)d_in[6];
  const float* xp_w   = (const float*)d_in[7];
  const float* dt_w   = (const float*)d_in[8];
  const float* dt_b   = (const float*)d_in[9];
  const float* A_log  = (const float*)d_in[10];
  const float* Dp     = (const float*)d_in[11];
  const float* out_w  = (const float*)d_in[12];
  const float* proj_w = (const float*)d_in[13];
  const float* proj_b = (const float*)d_in[14];
  const float* skipv  = (const float*)d_in[15];
  float* out = (float*)d_out;
  float* ws  = (float*)d_ws;

  float* xnb = ws;                                   // NJ*L*128   (2.10M f)
  float* xzr = xnb + (size_t)NJ*LSEQ*128;            // NSEQ*L*64  (4.19M f) dead after k2 -> pb,eb
  float* zb  = xzr + (size_t)NSEQ*LSEQ*64;           // NSEQ*L*64  z (read-only after k1)
  float* dxb = zb  + (size_t)NSEQ*LSEQ*64;           // NSEQ*L*64*2 packed (dl,xi)
  float* bmb = dxb + (size_t)NSEQ*LSEQ*128;          // NSEQ*L*16
  float* cmb = bmb + (size_t)NSEQ*LSEQ*16;           // NSEQ*L*16
  float* xmb = cmb + (size_t)NSEQ*LSEQ*16;           // NJ*L*128
  // pb/eb live in a region DISJOINT from xzr (k2 reads xzr while writing pb/eb)
  float* pb  = xmb + (size_t)NJ*LSEQ*128;            // NSEQ*NC*1024 = 2.10M; hs in-place
  float* eb  = pb  + (size_t)NSEQ*NC*1024;           // 2.10M
  float* hsb = pb;

  hipLaunchKernelGGL(k1_ln_inproj, dim3(LSEQ/32,NJ), dim3(256), 0, stream,
                     x,did,ln_g,ln_b,in_w,xnb,xzr,zb);
  hipLaunchKernelGGL(k2_conv_xproj_pe, dim3(NC,NSEQ), dim3(256), 0, stream,
                     did,conv_w,conv_b,xp_w,dt_w,dt_b,A_log,xzr,dxb,bmb,cmb,pb,eb);
  hipLaunchKernelGGL(k3b_combine, dim3(4,NSEQ), dim3(256), 0, stream, pb,eb);
  hipLaunchKernelGGL(k3c4_scan_outproj, dim3(NC/2,NSEQ), dim3(256), 0, stream,
                     did,A_log,Dp,dxb,bmb,cmb,zb,hsb,out_w,skipv,xnb,xmb);
  hipLaunchKernelGGL(k5_ln2_proj, dim3(LSEQ/16,2), dim3(256), 0, stream,
                     did,ln_g,ln_b,proj_w,proj_b,xmb,out);
}